// Round 6
// baseline (2323.234 us; speedup 1.0000x reference)
//
#include <hip/hip_runtime.h>
#include <math.h>

// GaussianMixtureLayer: EM loop (<=8 iters, device-side convergence flag) +
// final update + Gaussian log-prob loss. Heavy GEMMs on bf16 MFMA (hi/lo
// 3-term split), operands in FRAGMENT ORDER (wave-contiguous dwordx4 loads).
//   k_quad   : Y = X Linv^T, w = ||y - t||^2 (+ fused num/sw or final loss)
//   k_scatter: S_k = (w.X)^T X   (NCHUNK=1024 to amortize the atomic flush)
//   k_chol   : LDS Cholesky; panel factorization is WAVE-SYNCHRONOUS in wave 0
//              registers (zero barriers per column; round-5's 256 block-wide
//              barriers were 880 cyc each = the whole 94 us)
//   k_trinv  : Linv columns (frag-order bf16 hi/lo) + t solve  [kept separate:
//              fusing into k_chol spilled to scratch in round 4]
//   k_update : closed-form mean/cov update + fused convergence flag

#define NS 16384
#define DD 128
#define KC 16
#define JITTER_ 1e-6f
#define EPS2_ 1e-6f            // (1e-3)^2 Frobenius convergence check
#define LOG_2PI_ 1.8378770664093454f
#define NCHUNK 1024            // scatter samples per block

typedef __attribute__((ext_vector_type(8))) short bf16x8;
typedef __attribute__((ext_vector_type(16))) float f32x16;

// workspace float offsets
enum : int {
  OFF_CUR_M  = 0,            // 16*128
  OFF_CS     = 2048,         // 16*128*128 (C, then S accumulator, then new C)
  OFF_LT     = 264192,       // fp32 L^T per k: LT[p][i] = L[i][p]
  OFF_INVD   = 526336,       // 1/L_ii
  OFF_T      = 528384,       // t_k = Linv_k m_k (fp32)
  OFF_LOGDET = 530432,
  OFF_SW     = 530448,
  OFF_NUM    = 530464,       // 16*128
  OFF_W      = 532512,       // w[k][n]
  OFF_LOSSK  = 794656,       // 16 per-k loss partials
  OFF_DIFFSQ = 794672,
  OFF_DONE   = 794673,       // int
  OFF_CTR    = 794674,       // int
  // frag-order bf16 arrays (ushort), 2 floats per 4 ushorts:
  OFF_XAH    = 794676,       // X row-side frags: [ng(512)][ec(4)][ks(2)][l(64)][8]
  OFF_XAL    = 1843252,
  OFF_XBH    = 2891828,      // X^T frags: [eg(4)][nb(1024)][l(64)][8]
  OFF_XBL    = 3940404,
  OFF_LBH    = 4988980,      // Linv frags per k: [k][dg(4)][ec(4)][ks(2)][l(64)][8]
  OFF_LBL    = 5120052,
  WS_FLOATS  = 5251124       // ~21 MB
};

__device__ __forceinline__ float bf2f(ushort u) {
  union { unsigned u; float f; } c; c.u = ((unsigned)u) << 16; return c.f;
}
__device__ __forceinline__ ushort f2bf_rne(float f) {
  union { float f; unsigned u; } c; c.f = f;
  unsigned r = c.u + 0x7fffu + ((c.u >> 16) & 1u);
  return (ushort)(r >> 16);
}
__device__ __forceinline__ ushort f2bf_trunc(float f) {
  union { float f; unsigned u; } c; c.f = f; return (ushort)(c.u >> 16);
}

// XOR-quad swizzle for 128x128 LDS matrix (k_chol).
__device__ __forceinline__ int swz(int r, int c) {
  return (r << 7) + ((((c >> 2) + r) & 31) << 2) + (c & 3);
}

// init state + one-time bf16 hi/lo split of X into frag-order XA (row side)
// and XB (transposed side). Block b handles samples 64b..64b+63.
__global__ __launch_bounds__(256) void k_init_split(const float* __restrict__ x,
                                                    const float* __restrict__ means,
                                                    const float* __restrict__ covs,
                                                    float* __restrict__ ws) {
  __shared__ float xt[64 * 132];
  int b = blockIdx.x, t = threadIdx.x;
  int idx = b * 256 + t;
  for (int i = idx; i < KC * DD * DD; i += 256 * 256) ws[OFF_CS + i] = covs[i];
  if (idx < KC * DD) ws[OFF_CUR_M + idx] = means[idx];
  if (idx == 0) {
    ws[OFF_DIFFSQ] = 0.f;
    ((int*)ws)[OFF_DONE] = 0;
    ((int*)ws)[OFF_CTR]  = 0;
  }
  int n0 = b * 64;
  for (int fi = t; fi < 2048; fi += 256) {
    int n = fi >> 5, q = (fi & 31) * 4;
    *(float4*)&xt[n * 132 + q] = *(const float4*)&x[(size_t)(n0 + n) * DD + q];
  }
  __syncthreads();
  ushort* __restrict__ XAH = (ushort*)(ws + OFF_XAH);
  ushort* __restrict__ XAL = (ushort*)(ws + OFF_XAL);
  ushort* __restrict__ XBH = (ushort*)(ws + OFF_XBH);
  ushort* __restrict__ XBL = (ushort*)(ws + OFF_XBL);
  // XA: n = 32*ng+(l&31), e = 32ec+16ks+8(l>>5)+j
  for (int s = t; s < 1024; s += 256) {
    int l = s & 63, ks = (s >> 6) & 1, ec = (s >> 7) & 3, ngl = (s >> 9) & 1;
    int nl = 32 * ngl + (l & 31);
    int e0 = 32 * ec + 16 * ks + 8 * (l >> 5);
    float vv[8];
    *(float4*)&vv[0] = *(const float4*)&xt[nl * 132 + e0];
    *(float4*)&vv[4] = *(const float4*)&xt[nl * 132 + e0 + 4];
    ushort h[8], lo[8];
    #pragma unroll
    for (int j = 0; j < 8; ++j) {
      h[j]  = f2bf_trunc(vv[j]);
      lo[j] = f2bf_rne(vv[j] - bf2f(h[j]));
    }
    size_t base = ((((size_t)((n0 >> 5) + ngl) * 4 + ec) * 2 + ks) * 64 + l) * 8;
    *(ushort4*)&XAH[base]     = make_ushort4(h[0], h[1], h[2], h[3]);
    *(ushort4*)&XAH[base + 4] = make_ushort4(h[4], h[5], h[6], h[7]);
    *(ushort4*)&XAL[base]     = make_ushort4(lo[0], lo[1], lo[2], lo[3]);
    *(ushort4*)&XAL[base + 4] = make_ushort4(lo[4], lo[5], lo[6], lo[7]);
  }
  // XB: e = 32eg+(l&31), n = 16*nb+8(l>>5)+j
  for (int s = t; s < 1024; s += 256) {
    int l = s & 63, nbl = (s >> 6) & 3, eg = (s >> 8) & 3;
    int e = 32 * eg + (l & 31);
    int nl = 16 * nbl + 8 * (l >> 5);
    ushort h[8], lo[8];
    #pragma unroll
    for (int j = 0; j < 8; ++j) {
      float v = xt[(nl + j) * 132 + e];
      h[j]  = f2bf_trunc(v);
      lo[j] = f2bf_rne(v - bf2f(h[j]));
    }
    size_t base = (((size_t)eg * (NS / 16) + (n0 >> 4) + nbl) * 64 + l) * 8;
    *(ushort4*)&XBH[base]     = make_ushort4(h[0], h[1], h[2], h[3]);
    *(ushort4*)&XBH[base + 4] = make_ushort4(h[4], h[5], h[6], h[7]);
    *(ushort4*)&XBL[base]     = make_ushort4(lo[0], lo[1], lo[2], lo[3]);
    *(ushort4*)&XBL[base + 4] = make_ushort4(lo[4], lo[5], lo[6], lo[7]);
  }
}

// Blocked right-looking Cholesky of C[k] (from OFF_CS) in LDS. Panel (128x32)
// factorization is done by wave 0 entirely in registers (2 rows/lane, __shfl
// broadcasts, ZERO barriers); trailing update uses all 256 threads. ~9
// barriers total vs ~260 in the naive version. Writes fp32 LT + 1/diag
// (+logdet/LOSSK-zero on final), zeroes S/num/sw accumulators.
__global__ __launch_bounds__(256) void k_chol(float* __restrict__ ws, int guarded, int final_pass) {
  if (guarded && ((const int*)ws)[OFF_DONE]) return;
  __shared__ float m[DD * DD];
  int k = blockIdx.x, t = threadIdx.x;
  int l = t & 63, wv = t >> 6;
  float* __restrict__ C = ws + OFF_CS + (size_t)k * DD * DD;
  for (int i = t; i < DD * DD; i += 256) {
    m[swz(i >> 7, i & 127)] = C[i];
    C[i] = 0.f;                      // becomes this iteration's S accumulator
  }
  if (t < DD) ws[OFF_NUM + k * DD + t] = 0.f;
  if (t == 0) {
    ws[OFF_SW + k] = 0.f;
    if (k == 0) ((int*)ws)[OFF_CTR] = 0;
    if (final_pass) ws[OFF_LOSSK + k] = 0.f;
  }
  __syncthreads();

  for (int P = 0; P < DD; P += 32) {
    if (wv == 0) {
      // wave-synchronous panel factorization: lane owns rows P+l and P+64+l
      int ra = P + l, rb = P + 64 + l;
      bool va = ra < DD, vb = rb < DD;
      float A[32], B[32];
      if (va) {
        #pragma unroll
        for (int q = 0; q < 8; ++q) {
          float4 v = *(const float4*)&m[swz(ra, P + 4 * q)];
          A[4*q+0] = v.x; A[4*q+1] = v.y; A[4*q+2] = v.z; A[4*q+3] = v.w;
        }
      }
      if (vb) {
        #pragma unroll
        for (int q = 0; q < 8; ++q) {
          float4 v = *(const float4*)&m[swz(rb, P + 4 * q)];
          B[4*q+0] = v.x; B[4*q+1] = v.y; B[4*q+2] = v.z; B[4*q+3] = v.w;
        }
      }
      #pragma unroll
      for (int jj = 0; jj < 32; ++jj) {
        float dj = __shfl(A[jj], jj, 64);      // current diag a[j][j]
        float sj = sqrtf(dj);
        float inv = 1.f / sj;
        if (va) {
          if (l == jj) A[jj] = sj;
          else if (l > jj) A[jj] *= inv;       // L[i][j] = a[i][j]/L[j][j]
        }
        if (vb) B[jj] *= inv;                  // rb > P+31 >= j always
        // rank-1 update of remaining panel columns: a[i][jj2] -= L[i][jj]*L[jj2][jj]
        #pragma unroll
        for (int jj2 = jj + 1; jj2 < 32; ++jj2) {
          float c = __shfl(A[jj], jj2, 64);    // L[jj2][jj] (lane jj2's row)
          if (va && l > jj) A[jj2] -= A[jj] * c;
          if (vb) B[jj2] -= B[jj] * c;
        }
      }
      if (va) {
        #pragma unroll
        for (int q = 0; q < 8; ++q)
          *(float4*)&m[swz(ra, P + 4 * q)] = make_float4(A[4*q], A[4*q+1], A[4*q+2], A[4*q+3]);
      }
      if (vb) {
        #pragma unroll
        for (int q = 0; q < 8; ++q)
          *(float4*)&m[swz(rb, P + 4 * q)] = make_float4(B[4*q], B[4*q+1], B[4*q+2], B[4*q+3]);
      }
    }
    __syncthreads();
    // trailing update: m[i][q] -= sum_{p in panel} L[i][p] L[q][p], i,q >= R0
    int R0 = P + 32;
    if (R0 < DD) {
      int s = DD - R0;
      int tq = R0 + (t & 31);
      for (int b = 0; b < s; b += 32) {
        int q = tq + b;
        float lq[32];
        #pragma unroll
        for (int p4 = 0; p4 < 8; ++p4) {
          float4 v = *(const float4*)&m[swz(q, P + 4 * p4)];
          lq[4*p4+0] = v.x; lq[4*p4+1] = v.y; lq[4*p4+2] = v.z; lq[4*p4+3] = v.w;
        }
        for (int i = R0 + (t >> 5); i < DD; i += 8) {
          float a = m[swz(i, q)];
          #pragma unroll
          for (int p4 = 0; p4 < 8; ++p4) {
            float4 v = *(const float4*)&m[swz(i, P + 4 * p4)];
            a -= v.x * lq[4*p4+0] + v.y * lq[4*p4+1] + v.z * lq[4*p4+2] + v.w * lq[4*p4+3];
          }
          m[swz(i, q)] = a;
        }
      }
    }
    __syncthreads();
  }

  float* __restrict__ LT = ws + OFF_LT + (size_t)k * DD * DD;
  for (int idx = t; idx < DD * DD; idx += 256) {
    int p = idx >> 7, i = idx & 127;
    LT[idx] = (i >= p) ? m[swz(i, p)] : 0.f;
  }
  if (t < DD) ws[OFF_INVD + k * DD + t] = 1.f / m[swz(t, t)];
  if (final_pass && t == 0) {
    float ld = 0.f;
    for (int i = 0; i < DD; ++i) ld += logf(m[swz(i, i)]);
    ws[OFF_LOGDET + k] = 2.f * ld;
  }
}

// Linv = L^{-1}: thread j owns column j (right-looking, register column,
// wave-uniform LT reads -> scalar loads). Writes frag-order bf16 hi/lo of
// Linv via LDS transpose (coalesced), plus fp32 t = Linv m.
__global__ __launch_bounds__(128) void k_trinv(float* __restrict__ ws, int guarded) {
  if (guarded && ((const int*)ws)[OFF_DONE]) return;
  __shared__ float Zs[DD * 129];   // Zs[j][i] = Linv[i][j]
  int k = blockIdx.x, j = threadIdx.x;
  const float* __restrict__ LT   = ws + OFF_LT + (size_t)k * DD * DD;
  const float* __restrict__ invd = ws + OFF_INVD + k * DD;
  float acc[DD];
  #pragma unroll
  for (int i = 0; i < DD; ++i) acc[i] = 0.f;
  #pragma unroll
  for (int p = 0; p < DD; ++p) {
    float zp = ((p == j) ? 1.f : 0.f) - acc[p];
    zp *= invd[p];                 // zero for p<j automatically
    Zs[j * 129 + p] = zp;
    #pragma unroll
    for (int i = p + 1; i < DD; ++i) acc[i] += LT[p * DD + i] * zp;
  }
  __syncthreads();
  // frag-order write: slot s -> (dg,ec,ks,l,j2); d=32dg+(l&31), e=32ec+16ks+8(l>>5)+j2
  ushort* __restrict__ LBH = (ushort*)(ws + OFF_LBH) + (size_t)k * 16384;
  ushort* __restrict__ LBL = (ushort*)(ws + OFF_LBL) + (size_t)k * 16384;
  for (int s = j; s < 16384; s += 128) {
    int j2 = s & 7, l = (s >> 3) & 63, ks = (s >> 9) & 1, ec = (s >> 10) & 3, dg = (s >> 12) & 3;
    int d = 32 * dg + (l & 31);
    int e = 32 * ec + 16 * ks + 8 * (l >> 5) + j2;
    float v = Zs[e * 129 + d];     // Linv[d][e]
    ushort h = f2bf_trunc(v);
    LBH[s] = h;
    LBL[s] = f2bf_rne(v - bf2f(h));
  }
  const float* __restrict__ mk = ws + OFF_CUR_M + k * DD;
  float s0 = 0.f, s1 = 0.f, s2 = 0.f, s3 = 0.f;
  for (int e = 0; e < DD; e += 4) {
    s0 += Zs[(e + 0) * 129 + j] * mk[e + 0];
    s1 += Zs[(e + 1) * 129 + j] * mk[e + 1];
    s2 += Zs[(e + 2) * 129 + j] * mk[e + 2];
    s3 += Zs[(e + 3) * 129 + j] * mk[e + 3];
  }
  ws[OFF_T + k * DD + j] = (s0 + s1) + (s2 + s3);
}

// w[n,k] = ||X Linv^T - t||^2. Block: 128 samples x full 128 d, 4 waves.
// All operand loads are wave-contiguous 1 KB dwordx4 from frag-order arrays.
__global__ __launch_bounds__(256) void k_quad(float* __restrict__ ws,
                                              const float* __restrict__ wts,
                                              int guarded, int final_pass) {
  if (guarded && ((const int*)ws)[OFF_DONE]) return;
  __shared__ float warr[128];
  int k = blockIdx.y, bx = blockIdx.x, t = threadIdx.x;
  int l = t & 63, wv = t >> 6;
  int n0 = bx * 128;
  const ushort* __restrict__ XAH = (const ushort*)(ws + OFF_XAH);
  const ushort* __restrict__ XAL = (const ushort*)(ws + OFF_XAL);
  const ushort* __restrict__ LBH = (const ushort*)(ws + OFF_LBH) + (size_t)k * 16384;
  const ushort* __restrict__ LBL = (const ushort*)(ws + OFF_LBL) + (size_t)k * 16384;
  f32x16 acc[4] = {};
  size_t ng4 = (size_t)(4 * bx + wv) * 4;
  #pragma unroll
  for (int ec = 0; ec < 4; ++ec) {
    #pragma unroll
    for (int ks = 0; ks < 2; ++ks) {
      size_t aoff = (((ng4 + ec) * 2 + ks) * 64 + l) * 8;
      bf16x8 ah = *(const bf16x8*)&XAH[aoff];
      bf16x8 al = *(const bf16x8*)&XAL[aoff];
      #pragma unroll
      for (int dg = 0; dg < 4; ++dg) {
        size_t boff = ((((size_t)dg * 4 + ec) * 2 + ks) * 64 + l) * 8;
        bf16x8 bh = *(const bf16x8*)&LBH[boff];
        bf16x8 bl = *(const bf16x8*)&LBL[boff];
        acc[dg] = __builtin_amdgcn_mfma_f32_32x32x16_bf16(ah, bh, acc[dg], 0, 0, 0);
        acc[dg] = __builtin_amdgcn_mfma_f32_32x32x16_bf16(ah, bl, acc[dg], 0, 0, 0);
        acc[dg] = __builtin_amdgcn_mfma_f32_32x32x16_bf16(al, bh, acc[dg], 0, 0, 0);
      }
    }
  }
  // epilogue: w per sample row = sum_d (y - t)^2
  float tv[4];
  #pragma unroll
  for (int c = 0; c < 4; ++c) tv[c] = ws[OFF_T + k * DD + 32 * c + (l & 31)];
  float part[16];
  #pragma unroll
  for (int r = 0; r < 16; ++r) {
    float s = 0.f;
    #pragma unroll
    for (int c = 0; c < 4; ++c) { float d = acc[c][r] - tv[c]; s += d * d; }
    part[r] = s;
  }
  #pragma unroll
  for (int mk2 = 1; mk2 < 32; mk2 <<= 1)
    #pragma unroll
    for (int r = 0; r < 16; ++r) part[r] += __shfl_xor(part[r], mk2, 64);
  int h = l >> 5;
  if ((l & 31) < 16) {
    int r = l & 31;
    int row = (r & 3) + 8 * (r >> 2) + 4 * h + 32 * wv;   // verified C/D layout
    warr[row] = part[r];
    ws[OFF_W + k * NS + n0 + row] = part[r];
  }
  __syncthreads();
  if (!final_pass) {
    if (t < 128) {
      int d = t;
      int e_ec = d >> 5, e_ks = (d >> 4) & 1, e_h = (d >> 3) & 1, e_j = d & 7;
      float s = 0.f;
      for (int n = 0; n < 128; ++n) {
        size_t a = ((((size_t)(4 * bx + (n >> 5)) * 4 + e_ec) * 2 + e_ks) * 64 +
                    ((e_h << 5) | (n & 31))) * 8 + e_j;
        s += warr[n] * (bf2f(XAH[a]) + bf2f(XAL[a]));
      }
      atomicAdd(&ws[OFF_NUM + k * DD + d], s);
    } else if (t == 128) {
      float s = 0.f;
      for (int n = 0; n < 128; ++n) s += warr[n];
      atomicAdd(&ws[OFF_SW + k], s);
    }
  } else {
    if (t < 64) {
      float s = warr[t] + warr[t + 64];
      #pragma unroll
      for (int mk2 = 1; mk2 < 64; mk2 <<= 1) s += __shfl_xor(s, mk2, 64);
      if (t == 0) atomicAdd(&ws[OFF_LOSSK + k], 0.5f * wts[k] * s);
    }
  }
}

// S_k += (w.X)^T X over NCHUNK samples; operands from frag-order XB arrays
// (wave-contiguous loads); A re-split with w on the fly in registers.
__global__ __launch_bounds__(256) void k_scatter(float* __restrict__ ws, int guarded) {
  if (guarded && ((const int*)ws)[OFF_DONE]) return;
  int k = blockIdx.y, chunk = blockIdx.x, t = threadIdx.x;
  int l = t & 63, dg = t >> 6;
  const ushort* __restrict__ XBH = (const ushort*)(ws + OFF_XBH);
  const ushort* __restrict__ XBL = (const ushort*)(ws + OFF_XBL);
  const float* __restrict__ wp = ws + OFF_W + k * NS + chunk * NCHUNK;
  f32x16 acc[4] = {};
  int nb0 = chunk * (NCHUNK / 16);
  int ko = (l >> 5) * 8;
  for (int st = 0; st < NCHUNK / 16; ++st) {
    size_t aoff = (((size_t)dg * (NS / 16) + nb0 + st) * 64 + l) * 8;
    bf16x8 th = *(const bf16x8*)&XBH[aoff];
    bf16x8 tl = *(const bf16x8*)&XBL[aoff];
    float4 w0 = *(const float4*)&wp[16 * st + ko];
    float4 w1 = *(const float4*)&wp[16 * st + ko + 4];
    float wj[8] = {w0.x, w0.y, w0.z, w0.w, w1.x, w1.y, w1.z, w1.w};
    bf16x8 ah, al;
    #pragma unroll
    for (int j = 0; j < 8; ++j) {
      float xf = bf2f((ushort)th[j]) + bf2f((ushort)tl[j]);
      float zf = wj[j] * xf;
      union { float f; unsigned u; } cz; cz.f = zf;
      ah[j] = (short)(ushort)(cz.u >> 16);
      union { unsigned u; float f; } ch; ch.u = cz.u & 0xffff0000u;
      al[j] = (short)f2bf_rne(zf - ch.f);
    }
    #pragma unroll
    for (int eg = 0; eg < 4; ++eg) {
      size_t boff = (((size_t)eg * (NS / 16) + nb0 + st) * 64 + l) * 8;
      bf16x8 bh = *(const bf16x8*)&XBH[boff];
      bf16x8 bl = *(const bf16x8*)&XBL[boff];
      acc[eg] = __builtin_amdgcn_mfma_f32_32x32x16_bf16(ah, bh, acc[eg], 0, 0, 0);
      acc[eg] = __builtin_amdgcn_mfma_f32_32x32x16_bf16(ah, bl, acc[eg], 0, 0, 0);
      acc[eg] = __builtin_amdgcn_mfma_f32_32x32x16_bf16(al, bh, acc[eg], 0, 0, 0);
    }
  }
  float* __restrict__ S = ws + OFF_CS + (size_t)k * DD * DD;
  int h = l >> 5;
  #pragma unroll
  for (int eg = 0; eg < 4; ++eg) {
    int e = 32 * eg + (l & 31);
    #pragma unroll
    for (int r = 0; r < 16; ++r) {
      int drow = 32 * dg + (r & 3) + 8 * (r >> 2) + 4 * h;
      atomicAdd(&S[drow * DD + e], acc[eg][r]);
    }
  }
}

// new_m = num/sw; new_C = (S - m num^T - num m^T + sw m m^T)/sw + jitter*I.
// Fused convergence flag via last-block counter.
__global__ __launch_bounds__(128) void k_update(float* __restrict__ ws, float* __restrict__ dout,
                                                int guarded, int write_out, int accum_diff) {
  if (guarded && ((const int*)ws)[OFF_DONE]) return;
  __shared__ float red[128];
  int k = blockIdx.x, e = threadIdx.x;
  float sw = ws[OFF_SW + k];
  float inv = 1.f / sw;
  float me = ws[OFF_CUR_M + k * DD + e];
  float ne = ws[OFF_NUM + k * DD + e];
  float* __restrict__ SC = ws + OFF_CS + (size_t)k * DD * DD;
  const float* __restrict__ cm = ws + OFF_CUR_M + k * DD;
  const float* __restrict__ nm = ws + OFF_NUM + k * DD;
  for (int d = 0; d < DD; ++d) {
    float md = cm[d];
    float nd = nm[d];
    float v = (SC[d * DD + e] - md * ne - nd * me + sw * md * me) * inv;
    if (d == e) v += JITTER_;
    SC[d * DD + e] = v;
    if (write_out) dout[1 + KC * DD + k * DD * DD + d * DD + e] = v;
  }
  __syncthreads();
  float newm = ne * inv;
  ws[OFF_CUR_M + k * DD + e] = newm;
  if (write_out) dout[1 + k * DD + e] = newm;
  if (accum_diff) {
    float dm = newm - me;
    red[e] = dm * dm;
    __syncthreads();
    for (int s2 = 64; s2 > 0; s2 >>= 1) {
      if (e < s2) red[e] += red[e + s2];
      __syncthreads();
    }
    if (e == 0) {
      atomicAdd(&ws[OFF_DIFFSQ], red[0]);
      __threadfence();
      int old = atomicAdd((int*)ws + OFF_CTR, 1);
      if (old == KC - 1) {                       // last block: evaluate flag
        float v = atomicAdd(&ws[OFF_DIFFSQ], 0.f);
        if (v <= EPS2_) atomicExch((int*)ws + OFF_DONE, 1);
        atomicExch(&ws[OFF_DIFFSQ], 0.f);
      }
    }
  }
}

__global__ void k_lossfin(const float* __restrict__ weights, const float* __restrict__ ws,
                          float* __restrict__ dout) {
  if (threadIdx.x == 0 && blockIdx.x == 0) {
    float base = 0.f;
    for (int k = 0; k < KC; ++k)
      base += weights[k] * 0.5f * (float)NS * ((float)DD * LOG_2PI_ + ws[OFF_LOGDET + k])
            + ws[OFF_LOSSK + k];
    dout[0] = base;
  }
}

extern "C" void kernel_launch(void* const* d_in, const int* in_sizes, int n_in,
                              void* d_out, int out_size, void* d_ws, size_t ws_size,
                              hipStream_t stream) {
  const float* x       = (const float*)d_in[0];
  const float* means   = (const float*)d_in[1];
  const float* covs    = (const float*)d_in[2];
  const float* weights = (const float*)d_in[3];
  float* out = (float*)d_out;
  float* ws  = (float*)d_ws;

  hipLaunchKernelGGL(k_init_split, dim3(NS / 64), dim3(256), 0, stream, x, means, covs, ws);

  // 8 guarded loop iterations + 1 unguarded final update (u==8)
  for (int u = 0; u < 9; ++u) {
    int guarded = (u < 8) ? 1 : 0;
    hipLaunchKernelGGL(k_chol,    dim3(16),      dim3(256), 0, stream, ws, guarded, 0);
    hipLaunchKernelGGL(k_trinv,   dim3(16),      dim3(128), 0, stream, ws, guarded);
    hipLaunchKernelGGL(k_quad,    dim3(128, 16), dim3(256), 0, stream, ws, weights, guarded, 0);
    hipLaunchKernelGGL(k_scatter, dim3(NS / NCHUNK, 16), dim3(256), 0, stream, ws, guarded);
    hipLaunchKernelGGL(k_update,  dim3(16),      dim3(128), 0, stream, ws, out, guarded,
                       (u == 8) ? 1 : 0, guarded);
  }

  // final log-prob: Cholesky/Linv of c_fin (+logdet), mahalanobis + loss
  hipLaunchKernelGGL(k_chol,    dim3(16),      dim3(256), 0, stream, ws, 0, 1);
  hipLaunchKernelGGL(k_trinv,   dim3(16),      dim3(128), 0, stream, ws, 0);
  hipLaunchKernelGGL(k_quad,    dim3(128, 16), dim3(256), 0, stream, ws, weights, 0, 1);
  hipLaunchKernelGGL(k_lossfin, dim3(1),       dim3(64),  0, stream, weights, ws, out);
}

// Round 7
// 1811.518 us; speedup vs baseline: 1.2825x; 1.2825x over previous
//
#include <hip/hip_runtime.h>
#include <math.h>

// GaussianMixtureLayer: EM loop (<=8 iters, device-side convergence flag) +
// final update + Gaussian log-prob loss. Heavy GEMMs on bf16 MFMA (hi/lo
// 3-term split), operands in FRAGMENT ORDER (wave-contiguous dwordx4 loads).
//   k_quad   : Y = X Linv^T, w = ||y - t||^2 (+ fused num/sw or final loss)
//   k_scatter: S_k = (w.X)^T X   (NCHUNK=1024 to amortize the atomic flush)
//   k_chol   : LDS Cholesky; PANEL=16 wave-synchronous factorization in wave-0
//              registers (A[16]+B[16]=32 VGPR; the PANEL=32 variant hit
//              VGPR=256 and spilled -> 165us. Width 16 keeps the allocator
//              happy and the shuffle chain 4x shorter.)
//   k_trinv  : Linv columns (frag-order bf16 hi/lo) + t solve  [kept separate:
//              fusing into k_chol spilled to scratch in round 4]
//   k_update : closed-form mean/cov update + fused convergence flag

#define NS 16384
#define DD 128
#define KC 16
#define JITTER_ 1e-6f
#define EPS2_ 1e-6f            // (1e-3)^2 Frobenius convergence check
#define LOG_2PI_ 1.8378770664093454f
#define NCHUNK 1024            // scatter samples per block

typedef __attribute__((ext_vector_type(8))) short bf16x8;
typedef __attribute__((ext_vector_type(16))) float f32x16;

// workspace float offsets
enum : int {
  OFF_CUR_M  = 0,            // 16*128
  OFF_CS     = 2048,         // 16*128*128 (C, then S accumulator, then new C)
  OFF_LT     = 264192,       // fp32 L^T per k: LT[p][i] = L[i][p]
  OFF_INVD   = 526336,       // 1/L_ii
  OFF_T      = 528384,       // t_k = Linv_k m_k (fp32)
  OFF_LOGDET = 530432,
  OFF_SW     = 530448,
  OFF_NUM    = 530464,       // 16*128
  OFF_W      = 532512,       // w[k][n]
  OFF_LOSSK  = 794656,       // 16 per-k loss partials
  OFF_DIFFSQ = 794672,
  OFF_DONE   = 794673,       // int
  OFF_CTR    = 794674,       // int
  // frag-order bf16 arrays (ushort), 2 floats per 4 ushorts:
  OFF_XAH    = 794676,       // X row-side frags: [ng(512)][ec(4)][ks(2)][l(64)][8]
  OFF_XAL    = 1843252,
  OFF_XBH    = 2891828,      // X^T frags: [eg(4)][nb(1024)][l(64)][8]
  OFF_XBL    = 3940404,
  OFF_LBH    = 4988980,      // Linv frags per k: [k][dg(4)][ec(4)][ks(2)][l(64)][8]
  OFF_LBL    = 5120052,
  WS_FLOATS  = 5251124       // ~21 MB
};

__device__ __forceinline__ float bf2f(ushort u) {
  union { unsigned u; float f; } c; c.u = ((unsigned)u) << 16; return c.f;
}
__device__ __forceinline__ ushort f2bf_rne(float f) {
  union { float f; unsigned u; } c; c.f = f;
  unsigned r = c.u + 0x7fffu + ((c.u >> 16) & 1u);
  return (ushort)(r >> 16);
}
__device__ __forceinline__ ushort f2bf_trunc(float f) {
  union { float f; unsigned u; } c; c.f = f; return (ushort)(c.u >> 16);
}

// XOR-quad swizzle for 128x128 LDS matrix (k_chol).
__device__ __forceinline__ int swz(int r, int c) {
  return (r << 7) + ((((c >> 2) + r) & 31) << 2) + (c & 3);
}

// init state + one-time bf16 hi/lo split of X into frag-order XA (row side)
// and XB (transposed side). Block b handles samples 64b..64b+63.
__global__ __launch_bounds__(256) void k_init_split(const float* __restrict__ x,
                                                    const float* __restrict__ means,
                                                    const float* __restrict__ covs,
                                                    float* __restrict__ ws) {
  __shared__ float xt[64 * 132];
  int b = blockIdx.x, t = threadIdx.x;
  int idx = b * 256 + t;
  for (int i = idx; i < KC * DD * DD; i += 256 * 256) ws[OFF_CS + i] = covs[i];
  if (idx < KC * DD) ws[OFF_CUR_M + idx] = means[idx];
  if (idx == 0) {
    ws[OFF_DIFFSQ] = 0.f;
    ((int*)ws)[OFF_DONE] = 0;
    ((int*)ws)[OFF_CTR]  = 0;
  }
  int n0 = b * 64;
  for (int fi = t; fi < 2048; fi += 256) {
    int n = fi >> 5, q = (fi & 31) * 4;
    *(float4*)&xt[n * 132 + q] = *(const float4*)&x[(size_t)(n0 + n) * DD + q];
  }
  __syncthreads();
  ushort* __restrict__ XAH = (ushort*)(ws + OFF_XAH);
  ushort* __restrict__ XAL = (ushort*)(ws + OFF_XAL);
  ushort* __restrict__ XBH = (ushort*)(ws + OFF_XBH);
  ushort* __restrict__ XBL = (ushort*)(ws + OFF_XBL);
  // XA: n = 32*ng+(l&31), e = 32ec+16ks+8(l>>5)+j
  for (int s = t; s < 1024; s += 256) {
    int l = s & 63, ks = (s >> 6) & 1, ec = (s >> 7) & 3, ngl = (s >> 9) & 1;
    int nl = 32 * ngl + (l & 31);
    int e0 = 32 * ec + 16 * ks + 8 * (l >> 5);
    float vv[8];
    *(float4*)&vv[0] = *(const float4*)&xt[nl * 132 + e0];
    *(float4*)&vv[4] = *(const float4*)&xt[nl * 132 + e0 + 4];
    ushort h[8], lo[8];
    #pragma unroll
    for (int j = 0; j < 8; ++j) {
      h[j]  = f2bf_trunc(vv[j]);
      lo[j] = f2bf_rne(vv[j] - bf2f(h[j]));
    }
    size_t base = ((((size_t)((n0 >> 5) + ngl) * 4 + ec) * 2 + ks) * 64 + l) * 8;
    *(ushort4*)&XAH[base]     = make_ushort4(h[0], h[1], h[2], h[3]);
    *(ushort4*)&XAH[base + 4] = make_ushort4(h[4], h[5], h[6], h[7]);
    *(ushort4*)&XAL[base]     = make_ushort4(lo[0], lo[1], lo[2], lo[3]);
    *(ushort4*)&XAL[base + 4] = make_ushort4(lo[4], lo[5], lo[6], lo[7]);
  }
  // XB: e = 32eg+(l&31), n = 16*nb+8(l>>5)+j
  for (int s = t; s < 1024; s += 256) {
    int l = s & 63, nbl = (s >> 6) & 3, eg = (s >> 8) & 3;
    int e = 32 * eg + (l & 31);
    int nl = 16 * nbl + 8 * (l >> 5);
    ushort h[8], lo[8];
    #pragma unroll
    for (int j = 0; j < 8; ++j) {
      float v = xt[(nl + j) * 132 + e];
      h[j]  = f2bf_trunc(v);
      lo[j] = f2bf_rne(v - bf2f(h[j]));
    }
    size_t base = (((size_t)eg * (NS / 16) + (n0 >> 4) + nbl) * 64 + l) * 8;
    *(ushort4*)&XBH[base]     = make_ushort4(h[0], h[1], h[2], h[3]);
    *(ushort4*)&XBH[base + 4] = make_ushort4(h[4], h[5], h[6], h[7]);
    *(ushort4*)&XBL[base]     = make_ushort4(lo[0], lo[1], lo[2], lo[3]);
    *(ushort4*)&XBL[base + 4] = make_ushort4(lo[4], lo[5], lo[6], lo[7]);
  }
}

// Blocked right-looking Cholesky of C[k] (from OFF_CS) in LDS. PANEL=16:
// wave 0 factorizes the 128x16 panel in registers (lane owns rows P+l and
// P+64+l; __shfl broadcasts; zero barriers per column), then all 256 threads
// apply the rank-16 trailing update. ~17 barriers total. Writes fp32 LT +
// 1/diag (+logdet/LOSSK-zero on final), zeroes S/num/sw accumulators.
__global__ __launch_bounds__(256) void k_chol(float* __restrict__ ws, int guarded, int final_pass) {
  if (guarded && ((const int*)ws)[OFF_DONE]) return;
  __shared__ float m[DD * DD];
  int k = blockIdx.x, t = threadIdx.x;
  int l = t & 63, wv = t >> 6;
  float* __restrict__ C = ws + OFF_CS + (size_t)k * DD * DD;
  for (int i = t; i < DD * DD; i += 256) {
    m[swz(i >> 7, i & 127)] = C[i];
    C[i] = 0.f;                      // becomes this iteration's S accumulator
  }
  if (t < DD) ws[OFF_NUM + k * DD + t] = 0.f;
  if (t == 0) {
    ws[OFF_SW + k] = 0.f;
    if (k == 0) ((int*)ws)[OFF_CTR] = 0;
    if (final_pass) ws[OFF_LOSSK + k] = 0.f;
  }
  __syncthreads();

  for (int P = 0; P < DD; P += 16) {
    if (wv == 0) {
      // wave-synchronous panel factorization: lane owns rows P+l and P+64+l
      int ra = P + l, rb = P + 64 + l;
      bool va = ra < DD, vb = rb < DD;
      float A[16], B[16];
      if (va) {
        #pragma unroll
        for (int q = 0; q < 4; ++q) {
          float4 v = *(const float4*)&m[swz(ra, P + 4 * q)];
          A[4*q+0] = v.x; A[4*q+1] = v.y; A[4*q+2] = v.z; A[4*q+3] = v.w;
        }
      }
      if (vb) {
        #pragma unroll
        for (int q = 0; q < 4; ++q) {
          float4 v = *(const float4*)&m[swz(rb, P + 4 * q)];
          B[4*q+0] = v.x; B[4*q+1] = v.y; B[4*q+2] = v.z; B[4*q+3] = v.w;
        }
      }
      #pragma unroll
      for (int jj = 0; jj < 16; ++jj) {
        float dj = __shfl(A[jj], jj, 64);      // current diag a[j][j]
        float sj = sqrtf(dj);
        float inv = 1.f / sj;
        if (va) {
          if (l == jj) A[jj] = sj;
          else if (l > jj) A[jj] *= inv;       // L[i][j] = a[i][j]/L[j][j]
        }
        if (vb) B[jj] *= inv;                  // rb >= P+64 > P+15 always
        // rank-1 update of remaining panel columns
        #pragma unroll
        for (int jj2 = jj + 1; jj2 < 16; ++jj2) {
          float c = __shfl(A[jj], jj2, 64);    // L[jj2][jj] (lane jj2's row)
          if (va && l > jj) A[jj2] -= A[jj] * c;
          if (vb) B[jj2] -= B[jj] * c;
        }
      }
      if (va) {
        #pragma unroll
        for (int q = 0; q < 4; ++q)
          *(float4*)&m[swz(ra, P + 4 * q)] = make_float4(A[4*q], A[4*q+1], A[4*q+2], A[4*q+3]);
      }
      if (vb) {
        #pragma unroll
        for (int q = 0; q < 4; ++q)
          *(float4*)&m[swz(rb, P + 4 * q)] = make_float4(B[4*q], B[4*q+1], B[4*q+2], B[4*q+3]);
      }
    }
    __syncthreads();
    // trailing update: m[i][q] -= sum_{p in panel} L[i][p] L[q][p], i,q >= R0
    int R0 = P + 16;
    if (R0 < DD) {
      int s = DD - R0;
      int tq = R0 + (t & 31);
      for (int b = 0; b < s; b += 32) {
        int q = tq + b;
        if (q < DD) {                          // s is a multiple of 16, not 32
          float lq[16];
          #pragma unroll
          for (int p4 = 0; p4 < 4; ++p4) {
            float4 v = *(const float4*)&m[swz(q, P + 4 * p4)];
            lq[4*p4+0] = v.x; lq[4*p4+1] = v.y; lq[4*p4+2] = v.z; lq[4*p4+3] = v.w;
          }
          for (int i = R0 + (t >> 5); i < DD; i += 8) {
            float a = m[swz(i, q)];
            #pragma unroll
            for (int p4 = 0; p4 < 4; ++p4) {
              float4 v = *(const float4*)&m[swz(i, P + 4 * p4)];
              a -= v.x * lq[4*p4+0] + v.y * lq[4*p4+1] + v.z * lq[4*p4+2] + v.w * lq[4*p4+3];
            }
            m[swz(i, q)] = a;
          }
        }
      }
    }
    __syncthreads();
  }

  float* __restrict__ LT = ws + OFF_LT + (size_t)k * DD * DD;
  for (int idx = t; idx < DD * DD; idx += 256) {
    int p = idx >> 7, i = idx & 127;
    LT[idx] = (i >= p) ? m[swz(i, p)] : 0.f;
  }
  if (t < DD) ws[OFF_INVD + k * DD + t] = 1.f / m[swz(t, t)];
  if (final_pass && t == 0) {
    float ld = 0.f;
    for (int i = 0; i < DD; ++i) ld += logf(m[swz(i, i)]);
    ws[OFF_LOGDET + k] = 2.f * ld;
  }
}

// Linv = L^{-1}: thread j owns column j (right-looking, register column,
// wave-uniform LT reads -> scalar loads). Writes frag-order bf16 hi/lo of
// Linv via LDS transpose (coalesced), plus fp32 t = Linv m.
__global__ __launch_bounds__(128) void k_trinv(float* __restrict__ ws, int guarded) {
  if (guarded && ((const int*)ws)[OFF_DONE]) return;
  __shared__ float Zs[DD * 129];   // Zs[j][i] = Linv[i][j]
  int k = blockIdx.x, j = threadIdx.x;
  const float* __restrict__ LT   = ws + OFF_LT + (size_t)k * DD * DD;
  const float* __restrict__ invd = ws + OFF_INVD + k * DD;
  float acc[DD];
  #pragma unroll
  for (int i = 0; i < DD; ++i) acc[i] = 0.f;
  #pragma unroll
  for (int p = 0; p < DD; ++p) {
    float zp = ((p == j) ? 1.f : 0.f) - acc[p];
    zp *= invd[p];                 // zero for p<j automatically
    Zs[j * 129 + p] = zp;
    #pragma unroll
    for (int i = p + 1; i < DD; ++i) acc[i] += LT[p * DD + i] * zp;
  }
  __syncthreads();
  // frag-order write: slot s -> (dg,ec,ks,l,j2); d=32dg+(l&31), e=32ec+16ks+8(l>>5)+j2
  ushort* __restrict__ LBH = (ushort*)(ws + OFF_LBH) + (size_t)k * 16384;
  ushort* __restrict__ LBL = (ushort*)(ws + OFF_LBL) + (size_t)k * 16384;
  for (int s = j; s < 16384; s += 128) {
    int j2 = s & 7, l = (s >> 3) & 63, ks = (s >> 9) & 1, ec = (s >> 10) & 3, dg = (s >> 12) & 3;
    int d = 32 * dg + (l & 31);
    int e = 32 * ec + 16 * ks + 8 * (l >> 5) + j2;
    float v = Zs[e * 129 + d];     // Linv[d][e]
    ushort h = f2bf_trunc(v);
    LBH[s] = h;
    LBL[s] = f2bf_rne(v - bf2f(h));
  }
  const float* __restrict__ mk = ws + OFF_CUR_M + k * DD;
  float s0 = 0.f, s1 = 0.f, s2 = 0.f, s3 = 0.f;
  for (int e = 0; e < DD; e += 4) {
    s0 += Zs[(e + 0) * 129 + j] * mk[e + 0];
    s1 += Zs[(e + 1) * 129 + j] * mk[e + 1];
    s2 += Zs[(e + 2) * 129 + j] * mk[e + 2];
    s3 += Zs[(e + 3) * 129 + j] * mk[e + 3];
  }
  ws[OFF_T + k * DD + j] = (s0 + s1) + (s2 + s3);
}

// w[n,k] = ||X Linv^T - t||^2. Block: 128 samples x full 128 d, 4 waves.
// All operand loads are wave-contiguous 1 KB dwordx4 from frag-order arrays.
__global__ __launch_bounds__(256) void k_quad(float* __restrict__ ws,
                                              const float* __restrict__ wts,
                                              int guarded, int final_pass) {
  if (guarded && ((const int*)ws)[OFF_DONE]) return;
  __shared__ float warr[128];
  int k = blockIdx.y, bx = blockIdx.x, t = threadIdx.x;
  int l = t & 63, wv = t >> 6;
  int n0 = bx * 128;
  const ushort* __restrict__ XAH = (const ushort*)(ws + OFF_XAH);
  const ushort* __restrict__ XAL = (const ushort*)(ws + OFF_XAL);
  const ushort* __restrict__ LBH = (const ushort*)(ws + OFF_LBH) + (size_t)k * 16384;
  const ushort* __restrict__ LBL = (const ushort*)(ws + OFF_LBL) + (size_t)k * 16384;
  f32x16 acc[4] = {};
  size_t ng4 = (size_t)(4 * bx + wv) * 4;
  #pragma unroll
  for (int ec = 0; ec < 4; ++ec) {
    #pragma unroll
    for (int ks = 0; ks < 2; ++ks) {
      size_t aoff = (((ng4 + ec) * 2 + ks) * 64 + l) * 8;
      bf16x8 ah = *(const bf16x8*)&XAH[aoff];
      bf16x8 al = *(const bf16x8*)&XAL[aoff];
      #pragma unroll
      for (int dg = 0; dg < 4; ++dg) {
        size_t boff = ((((size_t)dg * 4 + ec) * 2 + ks) * 64 + l) * 8;
        bf16x8 bh = *(const bf16x8*)&LBH[boff];
        bf16x8 bl = *(const bf16x8*)&LBL[boff];
        acc[dg] = __builtin_amdgcn_mfma_f32_32x32x16_bf16(ah, bh, acc[dg], 0, 0, 0);
        acc[dg] = __builtin_amdgcn_mfma_f32_32x32x16_bf16(ah, bl, acc[dg], 0, 0, 0);
        acc[dg] = __builtin_amdgcn_mfma_f32_32x32x16_bf16(al, bh, acc[dg], 0, 0, 0);
      }
    }
  }
  // epilogue: w per sample row = sum_d (y - t)^2
  float tv[4];
  #pragma unroll
  for (int c = 0; c < 4; ++c) tv[c] = ws[OFF_T + k * DD + 32 * c + (l & 31)];
  float part[16];
  #pragma unroll
  for (int r = 0; r < 16; ++r) {
    float s = 0.f;
    #pragma unroll
    for (int c = 0; c < 4; ++c) { float d = acc[c][r] - tv[c]; s += d * d; }
    part[r] = s;
  }
  #pragma unroll
  for (int mk2 = 1; mk2 < 32; mk2 <<= 1)
    #pragma unroll
    for (int r = 0; r < 16; ++r) part[r] += __shfl_xor(part[r], mk2, 64);
  int h = l >> 5;
  if ((l & 31) < 16) {
    int r = l & 31;
    int row = (r & 3) + 8 * (r >> 2) + 4 * h + 32 * wv;   // verified C/D layout
    warr[row] = part[r];
    ws[OFF_W + k * NS + n0 + row] = part[r];
  }
  __syncthreads();
  if (!final_pass) {
    if (t < 128) {
      int d = t;
      int e_ec = d >> 5, e_ks = (d >> 4) & 1, e_h = (d >> 3) & 1, e_j = d & 7;
      float s = 0.f;
      for (int n = 0; n < 128; ++n) {
        size_t a = ((((size_t)(4 * bx + (n >> 5)) * 4 + e_ec) * 2 + e_ks) * 64 +
                    ((e_h << 5) | (n & 31))) * 8 + e_j;
        s += warr[n] * (bf2f(XAH[a]) + bf2f(XAL[a]));
      }
      atomicAdd(&ws[OFF_NUM + k * DD + d], s);
    } else if (t == 128) {
      float s = 0.f;
      for (int n = 0; n < 128; ++n) s += warr[n];
      atomicAdd(&ws[OFF_SW + k], s);
    }
  } else {
    if (t < 64) {
      float s = warr[t] + warr[t + 64];
      #pragma unroll
      for (int mk2 = 1; mk2 < 64; mk2 <<= 1) s += __shfl_xor(s, mk2, 64);
      if (t == 0) atomicAdd(&ws[OFF_LOSSK + k], 0.5f * wts[k] * s);
    }
  }
}

// S_k += (w.X)^T X over NCHUNK samples; operands from frag-order XB arrays
// (wave-contiguous loads); A re-split with w on the fly in registers.
__global__ __launch_bounds__(256) void k_scatter(float* __restrict__ ws, int guarded) {
  if (guarded && ((const int*)ws)[OFF_DONE]) return;
  int k = blockIdx.y, chunk = blockIdx.x, t = threadIdx.x;
  int l = t & 63, dg = t >> 6;
  const ushort* __restrict__ XBH = (const ushort*)(ws + OFF_XBH);
  const ushort* __restrict__ XBL = (const ushort*)(ws + OFF_XBL);
  const float* __restrict__ wp = ws + OFF_W + k * NS + chunk * NCHUNK;
  f32x16 acc[4] = {};
  int nb0 = chunk * (NCHUNK / 16);
  int ko = (l >> 5) * 8;
  for (int st = 0; st < NCHUNK / 16; ++st) {
    size_t aoff = (((size_t)dg * (NS / 16) + nb0 + st) * 64 + l) * 8;
    bf16x8 th = *(const bf16x8*)&XBH[aoff];
    bf16x8 tl = *(const bf16x8*)&XBL[aoff];
    float4 w0 = *(const float4*)&wp[16 * st + ko];
    float4 w1 = *(const float4*)&wp[16 * st + ko + 4];
    float wj[8] = {w0.x, w0.y, w0.z, w0.w, w1.x, w1.y, w1.z, w1.w};
    bf16x8 ah, al;
    #pragma unroll
    for (int j = 0; j < 8; ++j) {
      float xf = bf2f((ushort)th[j]) + bf2f((ushort)tl[j]);
      float zf = wj[j] * xf;
      union { float f; unsigned u; } cz; cz.f = zf;
      ah[j] = (short)(ushort)(cz.u >> 16);
      union { unsigned u; float f; } ch; ch.u = cz.u & 0xffff0000u;
      al[j] = (short)f2bf_rne(zf - ch.f);
    }
    #pragma unroll
    for (int eg = 0; eg < 4; ++eg) {
      size_t boff = (((size_t)eg * (NS / 16) + nb0 + st) * 64 + l) * 8;
      bf16x8 bh = *(const bf16x8*)&XBH[boff];
      bf16x8 bl = *(const bf16x8*)&XBL[boff];
      acc[eg] = __builtin_amdgcn_mfma_f32_32x32x16_bf16(ah, bh, acc[eg], 0, 0, 0);
      acc[eg] = __builtin_amdgcn_mfma_f32_32x32x16_bf16(ah, bl, acc[eg], 0, 0, 0);
      acc[eg] = __builtin_amdgcn_mfma_f32_32x32x16_bf16(al, bh, acc[eg], 0, 0, 0);
    }
  }
  float* __restrict__ S = ws + OFF_CS + (size_t)k * DD * DD;
  int h = l >> 5;
  #pragma unroll
  for (int eg = 0; eg < 4; ++eg) {
    int e = 32 * eg + (l & 31);
    #pragma unroll
    for (int r = 0; r < 16; ++r) {
      int drow = 32 * dg + (r & 3) + 8 * (r >> 2) + 4 * h;
      atomicAdd(&S[drow * DD + e], acc[eg][r]);
    }
  }
}

// new_m = num/sw; new_C = (S - m num^T - num m^T + sw m m^T)/sw + jitter*I.
// Fused convergence flag via last-block counter.
__global__ __launch_bounds__(128) void k_update(float* __restrict__ ws, float* __restrict__ dout,
                                                int guarded, int write_out, int accum_diff) {
  if (guarded && ((const int*)ws)[OFF_DONE]) return;
  __shared__ float red[128];
  int k = blockIdx.x, e = threadIdx.x;
  float sw = ws[OFF_SW + k];
  float inv = 1.f / sw;
  float me = ws[OFF_CUR_M + k * DD + e];
  float ne = ws[OFF_NUM + k * DD + e];
  float* __restrict__ SC = ws + OFF_CS + (size_t)k * DD * DD;
  const float* __restrict__ cm = ws + OFF_CUR_M + k * DD;
  const float* __restrict__ nm = ws + OFF_NUM + k * DD;
  for (int d = 0; d < DD; ++d) {
    float md = cm[d];
    float nd = nm[d];
    float v = (SC[d * DD + e] - md * ne - nd * me + sw * md * me) * inv;
    if (d == e) v += JITTER_;
    SC[d * DD + e] = v;
    if (write_out) dout[1 + KC * DD + k * DD * DD + d * DD + e] = v;
  }
  __syncthreads();
  float newm = ne * inv;
  ws[OFF_CUR_M + k * DD + e] = newm;
  if (write_out) dout[1 + k * DD + e] = newm;
  if (accum_diff) {
    float dm = newm - me;
    red[e] = dm * dm;
    __syncthreads();
    for (int s2 = 64; s2 > 0; s2 >>= 1) {
      if (e < s2) red[e] += red[e + s2];
      __syncthreads();
    }
    if (e == 0) {
      atomicAdd(&ws[OFF_DIFFSQ], red[0]);
      __threadfence();
      int old = atomicAdd((int*)ws + OFF_CTR, 1);
      if (old == KC - 1) {                       // last block: evaluate flag
        float v = atomicAdd(&ws[OFF_DIFFSQ], 0.f);
        if (v <= EPS2_) atomicExch((int*)ws + OFF_DONE, 1);
        atomicExch(&ws[OFF_DIFFSQ], 0.f);
      }
    }
  }
}

__global__ void k_lossfin(const float* __restrict__ weights, const float* __restrict__ ws,
                          float* __restrict__ dout) {
  if (threadIdx.x == 0 && blockIdx.x == 0) {
    float base = 0.f;
    for (int k = 0; k < KC; ++k)
      base += weights[k] * 0.5f * (float)NS * ((float)DD * LOG_2PI_ + ws[OFF_LOGDET + k])
            + ws[OFF_LOSSK + k];
    dout[0] = base;
  }
}

extern "C" void kernel_launch(void* const* d_in, const int* in_sizes, int n_in,
                              void* d_out, int out_size, void* d_ws, size_t ws_size,
                              hipStream_t stream) {
  const float* x       = (const float*)d_in[0];
  const float* means   = (const float*)d_in[1];
  const float* covs    = (const float*)d_in[2];
  const float* weights = (const float*)d_in[3];
  float* out = (float*)d_out;
  float* ws  = (float*)d_ws;

  hipLaunchKernelGGL(k_init_split, dim3(NS / 64), dim3(256), 0, stream, x, means, covs, ws);

  // 8 guarded loop iterations + 1 unguarded final update (u==8)
  for (int u = 0; u < 9; ++u) {
    int guarded = (u < 8) ? 1 : 0;
    hipLaunchKernelGGL(k_chol,    dim3(16),      dim3(256), 0, stream, ws, guarded, 0);
    hipLaunchKernelGGL(k_trinv,   dim3(16),      dim3(128), 0, stream, ws, guarded);
    hipLaunchKernelGGL(k_quad,    dim3(128, 16), dim3(256), 0, stream, ws, weights, guarded, 0);
    hipLaunchKernelGGL(k_scatter, dim3(NS / NCHUNK, 16), dim3(256), 0, stream, ws, guarded);
    hipLaunchKernelGGL(k_update,  dim3(16),      dim3(128), 0, stream, ws, out, guarded,
                       (u == 8) ? 1 : 0, guarded);
  }

  // final log-prob: Cholesky/Linv of c_fin (+logdet), mahalanobis + loss
  hipLaunchKernelGGL(k_chol,    dim3(16),      dim3(256), 0, stream, ws, 0, 1);
  hipLaunchKernelGGL(k_trinv,   dim3(16),      dim3(128), 0, stream, ws, 0);
  hipLaunchKernelGGL(k_quad,    dim3(128, 16), dim3(256), 0, stream, ws, weights, 0, 1);
  hipLaunchKernelGGL(k_lossfin, dim3(1),       dim3(64),  0, stream, weights, ws, out);
}

// Round 8
// 1525.651 us; speedup vs baseline: 1.5228x; 1.1874x over previous
//
#include <hip/hip_runtime.h>
#include <math.h>

// GaussianMixtureLayer: EM loop (<=8 iters, device-side convergence flag) +
// final update + Gaussian log-prob loss. Heavy GEMMs on bf16 MFMA (hi/lo
// 3-term split), operands in FRAGMENT ORDER (wave-contiguous dwordx4 loads).
//   k_quad   : Y = X Linv^T, w = ||y - t||^2 (+ fused num/sw or final loss)
//   k_scatter: S_k = (w.X)^T X   (NCHUNK=1024 to amortize the atomic flush)
//   k_chol   : LDS Cholesky; PANEL=16 wave-synchronous factorization
//   k_trinv  : TWO-LEVEL blocked Linv: parallel 64x64 diag inverses (short
//              register solves) + two cooperative 64^3 LDS GEMMs.
//              [round-7's monolithic 128-col solve was I$-bound: ~100KB
//               unrolled body -> 88us at 0.6% VALUBusy]
//   k_update : closed-form mean/cov update + fused convergence flag

#define NS 16384
#define DD 128
#define KC 16
#define JITTER_ 1e-6f
#define EPS2_ 1e-6f            // (1e-3)^2 Frobenius convergence check
#define LOG_2PI_ 1.8378770664093454f
#define NCHUNK 1024            // scatter samples per block

typedef __attribute__((ext_vector_type(8))) short bf16x8;
typedef __attribute__((ext_vector_type(16))) float f32x16;

// workspace float offsets
enum : int {
  OFF_CUR_M  = 0,            // 16*128
  OFF_CS     = 2048,         // 16*128*128 (C, then S accumulator, then new C)
  OFF_LT     = 264192,       // fp32 L^T per k: LT[p][i] = L[i][p]
  OFF_INVD   = 526336,       // 1/L_ii
  OFF_T      = 528384,       // t_k = Linv_k m_k (fp32)
  OFF_LOGDET = 530432,
  OFF_SW     = 530448,
  OFF_NUM    = 530464,       // 16*128
  OFF_W      = 532512,       // w[k][n]
  OFF_LOSSK  = 794656,       // 16 per-k loss partials
  OFF_DIFFSQ = 794672,
  OFF_DONE   = 794673,       // int
  OFF_CTR    = 794674,       // int
  // frag-order bf16 arrays (ushort), 2 floats per 4 ushorts:
  OFF_XAH    = 794676,       // X row-side frags: [ng(512)][ec(4)][ks(2)][l(64)][8]
  OFF_XAL    = 1843252,
  OFF_XBH    = 2891828,      // X^T frags: [eg(4)][nb(1024)][l(64)][8]
  OFF_XBL    = 3940404,
  OFF_LBH    = 4988980,      // Linv frags per k: [k][dg(4)][ec(4)][ks(2)][l(64)][8]
  OFF_LBL    = 5120052,
  WS_FLOATS  = 5251124       // ~21 MB
};

__device__ __forceinline__ float bf2f(ushort u) {
  union { unsigned u; float f; } c; c.u = ((unsigned)u) << 16; return c.f;
}
__device__ __forceinline__ ushort f2bf_rne(float f) {
  union { float f; unsigned u; } c; c.f = f;
  unsigned r = c.u + 0x7fffu + ((c.u >> 16) & 1u);
  return (ushort)(r >> 16);
}
__device__ __forceinline__ ushort f2bf_trunc(float f) {
  union { float f; unsigned u; } c; c.f = f; return (ushort)(c.u >> 16);
}

// XOR-quad swizzle for 128x128 LDS matrix (k_chol).
__device__ __forceinline__ int swz(int r, int c) {
  return (r << 7) + ((((c >> 2) + r) & 31) << 2) + (c & 3);
}

// init state + one-time bf16 hi/lo split of X into frag-order XA (row side)
// and XB (transposed side). Block b handles samples 64b..64b+63.
__global__ __launch_bounds__(256) void k_init_split(const float* __restrict__ x,
                                                    const float* __restrict__ means,
                                                    const float* __restrict__ covs,
                                                    float* __restrict__ ws) {
  __shared__ float xt[64 * 132];
  int b = blockIdx.x, t = threadIdx.x;
  int idx = b * 256 + t;
  for (int i = idx; i < KC * DD * DD; i += 256 * 256) ws[OFF_CS + i] = covs[i];
  if (idx < KC * DD) ws[OFF_CUR_M + idx] = means[idx];
  if (idx == 0) {
    ws[OFF_DIFFSQ] = 0.f;
    ((int*)ws)[OFF_DONE] = 0;
    ((int*)ws)[OFF_CTR]  = 0;
  }
  int n0 = b * 64;
  for (int fi = t; fi < 2048; fi += 256) {
    int n = fi >> 5, q = (fi & 31) * 4;
    *(float4*)&xt[n * 132 + q] = *(const float4*)&x[(size_t)(n0 + n) * DD + q];
  }
  __syncthreads();
  ushort* __restrict__ XAH = (ushort*)(ws + OFF_XAH);
  ushort* __restrict__ XAL = (ushort*)(ws + OFF_XAL);
  ushort* __restrict__ XBH = (ushort*)(ws + OFF_XBH);
  ushort* __restrict__ XBL = (ushort*)(ws + OFF_XBL);
  // XA: n = 32*ng+(l&31), e = 32ec+16ks+8(l>>5)+j
  for (int s = t; s < 1024; s += 256) {
    int l = s & 63, ks = (s >> 6) & 1, ec = (s >> 7) & 3, ngl = (s >> 9) & 1;
    int nl = 32 * ngl + (l & 31);
    int e0 = 32 * ec + 16 * ks + 8 * (l >> 5);
    float vv[8];
    *(float4*)&vv[0] = *(const float4*)&xt[nl * 132 + e0];
    *(float4*)&vv[4] = *(const float4*)&xt[nl * 132 + e0 + 4];
    ushort h[8], lo[8];
    #pragma unroll
    for (int j = 0; j < 8; ++j) {
      h[j]  = f2bf_trunc(vv[j]);
      lo[j] = f2bf_rne(vv[j] - bf2f(h[j]));
    }
    size_t base = ((((size_t)((n0 >> 5) + ngl) * 4 + ec) * 2 + ks) * 64 + l) * 8;
    *(ushort4*)&XAH[base]     = make_ushort4(h[0], h[1], h[2], h[3]);
    *(ushort4*)&XAH[base + 4] = make_ushort4(h[4], h[5], h[6], h[7]);
    *(ushort4*)&XAL[base]     = make_ushort4(lo[0], lo[1], lo[2], lo[3]);
    *(ushort4*)&XAL[base + 4] = make_ushort4(lo[4], lo[5], lo[6], lo[7]);
  }
  // XB: e = 32eg+(l&31), n = 16*nb+8(l>>5)+j
  for (int s = t; s < 1024; s += 256) {
    int l = s & 63, nbl = (s >> 6) & 3, eg = (s >> 8) & 3;
    int e = 32 * eg + (l & 31);
    int nl = 16 * nbl + 8 * (l >> 5);
    ushort h[8], lo[8];
    #pragma unroll
    for (int j = 0; j < 8; ++j) {
      float v = xt[(nl + j) * 132 + e];
      h[j]  = f2bf_trunc(v);
      lo[j] = f2bf_rne(v - bf2f(h[j]));
    }
    size_t base = (((size_t)eg * (NS / 16) + (n0 >> 4) + nbl) * 64 + l) * 8;
    *(ushort4*)&XBH[base]     = make_ushort4(h[0], h[1], h[2], h[3]);
    *(ushort4*)&XBH[base + 4] = make_ushort4(h[4], h[5], h[6], h[7]);
    *(ushort4*)&XBL[base]     = make_ushort4(lo[0], lo[1], lo[2], lo[3]);
    *(ushort4*)&XBL[base + 4] = make_ushort4(lo[4], lo[5], lo[6], lo[7]);
  }
}

// Blocked right-looking Cholesky of C[k] (from OFF_CS) in LDS. PANEL=16:
// wave 0 factorizes the 128x16 panel in registers, 256 threads apply the
// rank-16 trailing update. Writes fp32 LT + 1/diag (+logdet on final),
// zeroes S/num/sw accumulators.
__global__ __launch_bounds__(256) void k_chol(float* __restrict__ ws, int guarded, int final_pass) {
  if (guarded && ((const int*)ws)[OFF_DONE]) return;
  __shared__ float m[DD * DD];
  int k = blockIdx.x, t = threadIdx.x;
  int l = t & 63, wv = t >> 6;
  float* __restrict__ C = ws + OFF_CS + (size_t)k * DD * DD;
  for (int i = t; i < DD * DD; i += 256) {
    m[swz(i >> 7, i & 127)] = C[i];
    C[i] = 0.f;                      // becomes this iteration's S accumulator
  }
  if (t < DD) ws[OFF_NUM + k * DD + t] = 0.f;
  if (t == 0) {
    ws[OFF_SW + k] = 0.f;
    if (k == 0) ((int*)ws)[OFF_CTR] = 0;
    if (final_pass) ws[OFF_LOSSK + k] = 0.f;
  }
  __syncthreads();

  for (int P = 0; P < DD; P += 16) {
    if (wv == 0) {
      int ra = P + l, rb = P + 64 + l;
      bool va = ra < DD, vb = rb < DD;
      float A[16], B[16];
      if (va) {
        #pragma unroll
        for (int q = 0; q < 4; ++q) {
          float4 v = *(const float4*)&m[swz(ra, P + 4 * q)];
          A[4*q+0] = v.x; A[4*q+1] = v.y; A[4*q+2] = v.z; A[4*q+3] = v.w;
        }
      }
      if (vb) {
        #pragma unroll
        for (int q = 0; q < 4; ++q) {
          float4 v = *(const float4*)&m[swz(rb, P + 4 * q)];
          B[4*q+0] = v.x; B[4*q+1] = v.y; B[4*q+2] = v.z; B[4*q+3] = v.w;
        }
      }
      #pragma unroll
      for (int jj = 0; jj < 16; ++jj) {
        float dj = __shfl(A[jj], jj, 64);
        float sj = sqrtf(dj);
        float inv = 1.f / sj;
        if (va) {
          if (l == jj) A[jj] = sj;
          else if (l > jj) A[jj] *= inv;
        }
        if (vb) B[jj] *= inv;
        #pragma unroll
        for (int jj2 = jj + 1; jj2 < 16; ++jj2) {
          float c = __shfl(A[jj], jj2, 64);
          if (va && l > jj) A[jj2] -= A[jj] * c;
          if (vb) B[jj2] -= B[jj] * c;
        }
      }
      if (va) {
        #pragma unroll
        for (int q = 0; q < 4; ++q)
          *(float4*)&m[swz(ra, P + 4 * q)] = make_float4(A[4*q], A[4*q+1], A[4*q+2], A[4*q+3]);
      }
      if (vb) {
        #pragma unroll
        for (int q = 0; q < 4; ++q)
          *(float4*)&m[swz(rb, P + 4 * q)] = make_float4(B[4*q], B[4*q+1], B[4*q+2], B[4*q+3]);
      }
    }
    __syncthreads();
    int R0 = P + 16;
    if (R0 < DD) {
      int s = DD - R0;
      int tq = R0 + (t & 31);
      for (int b = 0; b < s; b += 32) {
        int q = tq + b;
        if (q < DD) {
          float lq[16];
          #pragma unroll
          for (int p4 = 0; p4 < 4; ++p4) {
            float4 v = *(const float4*)&m[swz(q, P + 4 * p4)];
            lq[4*p4+0] = v.x; lq[4*p4+1] = v.y; lq[4*p4+2] = v.z; lq[4*p4+3] = v.w;
          }
          for (int i = R0 + (t >> 5); i < DD; i += 8) {
            float a = m[swz(i, q)];
            #pragma unroll
            for (int p4 = 0; p4 < 4; ++p4) {
              float4 v = *(const float4*)&m[swz(i, P + 4 * p4)];
              a -= v.x * lq[4*p4+0] + v.y * lq[4*p4+1] + v.z * lq[4*p4+2] + v.w * lq[4*p4+3];
            }
            m[swz(i, q)] = a;
          }
        }
      }
    }
    __syncthreads();
  }

  float* __restrict__ LT = ws + OFF_LT + (size_t)k * DD * DD;
  for (int idx = t; idx < DD * DD; idx += 256) {
    int p = idx >> 7, i = idx & 127;
    LT[idx] = (i >= p) ? m[swz(i, p)] : 0.f;
  }
  if (t < DD) ws[OFF_INVD + k * DD + t] = 1.f / m[swz(t, t)];
  if (final_pass && t == 0) {
    float ld = 0.f;
    for (int i = 0; i < DD; ++i) ld += logf(m[swz(i, i)]);
    ws[OFF_LOGDET + k] = 2.f * ld;
  }
}

// Two-level blocked triangular inverse. L = [[A,0],[C,B]] (64x64 blocks):
//   Linv = [[Ainv, 0], [-Binv C Ainv, Binv]].
// Phase 1: waves 0/1 invert A/B in parallel (thread=column, acc[64] regs,
//          ONE shared unrolled triangle ~2k FMA; base pointers select half);
//          threads 128-255 stage C into LDS + zero Linv's upper-right block.
// Phase 2: W = C*Ainv (64^3 cooperative LDS GEMM, 4x4 tiles, b128 reads).
// Phase 3: Linv21 = -Binv*W (same shape).
// Phase 4: t = Linv*m (GEMV) + frag-order bf16 hi/lo writes.
__global__ __launch_bounds__(256) void k_trinv(float* __restrict__ ws, int guarded) {
  if (guarded && ((const int*)ws)[OFF_DONE]) return;
  __shared__ float Zs[DD * 132];   // Linv row-major: Zs[d*132+e] = Linv[d][e]
  __shared__ float Cs[64 * 68];    // Cs[q*68+i] = C[i][q] = L[64+i][q]
  __shared__ float Ws[64 * 68];    // Ws[i*68+j] = W[i][j]
  int k = blockIdx.x, t = threadIdx.x;
  const float* __restrict__ LT   = ws + OFF_LT + (size_t)k * DD * DD;
  const float* __restrict__ invd = ws + OFF_INVD + k * DD;
  if (t < 128) {
    int h = t >> 6, j = t & 63;                    // h uniform per wave
    const float* __restrict__ Lh = LT + (h * 64) * DD + h * 64;  // Lh[p*DD+i]=halfL[i][p]
    const float* __restrict__ dv = invd + h * 64;
    float* __restrict__ Zh = Zs + (h * 64) * 132 + h * 64;
    float acc[64];
    #pragma unroll
    for (int i = 0; i < 64; ++i) acc[i] = 0.f;
    #pragma unroll
    for (int p = 0; p < 64; ++p) {
      float zp = (((p == j) ? 1.f : 0.f) - acc[p]) * dv[p];
      Zh[p * 132 + j] = zp;                        // Linv_half[p][j] (0 for p<j)
      #pragma unroll
      for (int i = p + 1; i < 64; ++i) acc[i] += Lh[p * DD + i] * zp;
    }
  } else {
    int u = t - 128;
    for (int s = u; s < 4096; s += 128) {
      int q = s >> 6, i = s & 63;
      Cs[q * 68 + i] = LT[q * DD + 64 + i];        // C[i][q]
      Zs[(s >> 6) * 132 + 64 + (s & 63)] = 0.f;    // upper-right zero block
    }
  }
  __syncthreads();
  int i0 = (t & 15) * 4, j0 = (t >> 4) * 4;
  {  // GEMM1: W = C * Ainv
    float acc[4][4] = {};
    for (int q = 0; q < 64; ++q) {
      float4 a = *(const float4*)&Cs[q * 68 + i0];       // C[i0..+3][q]
      float4 b = *(const float4*)&Zs[q * 132 + j0];      // Ainv[q][j0..+3]
      float av[4] = {a.x, a.y, a.z, a.w}, bv[4] = {b.x, b.y, b.z, b.w};
      #pragma unroll
      for (int r = 0; r < 4; ++r)
        #pragma unroll
        for (int c = 0; c < 4; ++c) acc[r][c] += av[r] * bv[c];
    }
    #pragma unroll
    for (int r = 0; r < 4; ++r)
      #pragma unroll
      for (int c = 0; c < 4; ++c) Ws[(i0 + r) * 68 + j0 + c] = acc[r][c];
  }
  __syncthreads();
  {  // GEMM2: Linv21 = -Binv * W
    float acc[4][4] = {};
    for (int q0 = 0; q0 < 64; q0 += 4) {
      float4 bi[4], wq[4];
      #pragma unroll
      for (int r = 0; r < 4; ++r)
        bi[r] = *(const float4*)&Zs[(64 + i0 + r) * 132 + 64 + q0];  // Binv[i0+r][q0..+3]
      #pragma unroll
      for (int s = 0; s < 4; ++s)
        wq[s] = *(const float4*)&Ws[(q0 + s) * 68 + j0];             // W[q0+s][j0..+3]
      #pragma unroll
      for (int r = 0; r < 4; ++r) {
        float br[4] = {bi[r].x, bi[r].y, bi[r].z, bi[r].w};
        #pragma unroll
        for (int s = 0; s < 4; ++s) {
          float wv2[4] = {wq[s].x, wq[s].y, wq[s].z, wq[s].w};
          #pragma unroll
          for (int c = 0; c < 4; ++c) acc[r][c] += br[s] * wv2[c];
        }
      }
    }
    #pragma unroll
    for (int r = 0; r < 4; ++r)
      #pragma unroll
      for (int c = 0; c < 4; ++c) Zs[(64 + i0 + r) * 132 + j0 + c] = -acc[r][c];
  }
  __syncthreads();
  if (t < 128) {   // t = Linv * m
    const float* __restrict__ mk = ws + OFF_CUR_M + k * DD;
    float s0 = 0.f;
    for (int e = 0; e < DD; e += 4) {
      float4 z = *(const float4*)&Zs[t * 132 + e];
      s0 += z.x * mk[e] + z.y * mk[e + 1] + z.z * mk[e + 2] + z.w * mk[e + 3];
    }
    ws[OFF_T + k * DD + t] = s0;
  }
  // frag-order bf16 writes: d=32dg+(l&31), e=32ec+16ks+8(l>>5)+j2
  ushort* __restrict__ LBH = (ushort*)(ws + OFF_LBH) + (size_t)k * 16384;
  ushort* __restrict__ LBL = (ushort*)(ws + OFF_LBL) + (size_t)k * 16384;
  for (int s = t; s < 16384; s += 256) {
    int j2 = s & 7, l = (s >> 3) & 63, ks2 = (s >> 9) & 1, ec = (s >> 10) & 3, dg = (s >> 12) & 3;
    int d = 32 * dg + (l & 31);
    int e = 32 * ec + 16 * ks2 + 8 * (l >> 5) + j2;
    float v = Zs[d * 132 + e];
    ushort hh = f2bf_trunc(v);
    LBH[s] = hh;
    LBL[s] = f2bf_rne(v - bf2f(hh));
  }
}

// w[n,k] = ||X Linv^T - t||^2. Block: 128 samples x full 128 d, 4 waves.
// All operand loads are wave-contiguous 1 KB dwordx4 from frag-order arrays.
__global__ __launch_bounds__(256) void k_quad(float* __restrict__ ws,
                                              const float* __restrict__ wts,
                                              int guarded, int final_pass) {
  if (guarded && ((const int*)ws)[OFF_DONE]) return;
  __shared__ float warr[128];
  int k = blockIdx.y, bx = blockIdx.x, t = threadIdx.x;
  int l = t & 63, wv = t >> 6;
  int n0 = bx * 128;
  const ushort* __restrict__ XAH = (const ushort*)(ws + OFF_XAH);
  const ushort* __restrict__ XAL = (const ushort*)(ws + OFF_XAL);
  const ushort* __restrict__ LBH = (const ushort*)(ws + OFF_LBH) + (size_t)k * 16384;
  const ushort* __restrict__ LBL = (const ushort*)(ws + OFF_LBL) + (size_t)k * 16384;
  f32x16 acc[4] = {};
  size_t ng4 = (size_t)(4 * bx + wv) * 4;
  #pragma unroll
  for (int ec = 0; ec < 4; ++ec) {
    #pragma unroll
    for (int ks = 0; ks < 2; ++ks) {
      size_t aoff = (((ng4 + ec) * 2 + ks) * 64 + l) * 8;
      bf16x8 ah = *(const bf16x8*)&XAH[aoff];
      bf16x8 al = *(const bf16x8*)&XAL[aoff];
      #pragma unroll
      for (int dg = 0; dg < 4; ++dg) {
        size_t boff = ((((size_t)dg * 4 + ec) * 2 + ks) * 64 + l) * 8;
        bf16x8 bh = *(const bf16x8*)&LBH[boff];
        bf16x8 bl = *(const bf16x8*)&LBL[boff];
        acc[dg] = __builtin_amdgcn_mfma_f32_32x32x16_bf16(ah, bh, acc[dg], 0, 0, 0);
        acc[dg] = __builtin_amdgcn_mfma_f32_32x32x16_bf16(ah, bl, acc[dg], 0, 0, 0);
        acc[dg] = __builtin_amdgcn_mfma_f32_32x32x16_bf16(al, bh, acc[dg], 0, 0, 0);
      }
    }
  }
  float tv[4];
  #pragma unroll
  for (int c = 0; c < 4; ++c) tv[c] = ws[OFF_T + k * DD + 32 * c + (l & 31)];
  float part[16];
  #pragma unroll
  for (int r = 0; r < 16; ++r) {
    float s = 0.f;
    #pragma unroll
    for (int c = 0; c < 4; ++c) { float d = acc[c][r] - tv[c]; s += d * d; }
    part[r] = s;
  }
  #pragma unroll
  for (int mk2 = 1; mk2 < 32; mk2 <<= 1)
    #pragma unroll
    for (int r = 0; r < 16; ++r) part[r] += __shfl_xor(part[r], mk2, 64);
  int h = l >> 5;
  if ((l & 31) < 16) {
    int r = l & 31;
    int row = (r & 3) + 8 * (r >> 2) + 4 * h + 32 * wv;   // verified C/D layout
    warr[row] = part[r];
    ws[OFF_W + k * NS + n0 + row] = part[r];
  }
  __syncthreads();
  if (!final_pass) {
    if (t < 128) {
      int d = t;
      int e_ec = d >> 5, e_ks = (d >> 4) & 1, e_h = (d >> 3) & 1, e_j = d & 7;
      float s = 0.f;
      for (int n = 0; n < 128; ++n) {
        size_t a = ((((size_t)(4 * bx + (n >> 5)) * 4 + e_ec) * 2 + e_ks) * 64 +
                    ((e_h << 5) | (n & 31))) * 8 + e_j;
        s += warr[n] * (bf2f(XAH[a]) + bf2f(XAL[a]));
      }
      atomicAdd(&ws[OFF_NUM + k * DD + d], s);
    } else if (t == 128) {
      float s = 0.f;
      for (int n = 0; n < 128; ++n) s += warr[n];
      atomicAdd(&ws[OFF_SW + k], s);
    }
  } else {
    if (t < 64) {
      float s = warr[t] + warr[t + 64];
      #pragma unroll
      for (int mk2 = 1; mk2 < 64; mk2 <<= 1) s += __shfl_xor(s, mk2, 64);
      if (t == 0) atomicAdd(&ws[OFF_LOSSK + k], 0.5f * wts[k] * s);
    }
  }
}

// S_k += (w.X)^T X over NCHUNK samples; operands from frag-order XB arrays
// (wave-contiguous loads); A re-split with w on the fly in registers.
__global__ __launch_bounds__(256) void k_scatter(float* __restrict__ ws, int guarded) {
  if (guarded && ((const int*)ws)[OFF_DONE]) return;
  int k = blockIdx.y, chunk = blockIdx.x, t = threadIdx.x;
  int l = t & 63, dg = t >> 6;
  const ushort* __restrict__ XBH = (const ushort*)(ws + OFF_XBH);
  const ushort* __restrict__ XBL = (const ushort*)(ws + OFF_XBL);
  const float* __restrict__ wp = ws + OFF_W + k * NS + chunk * NCHUNK;
  f32x16 acc[4] = {};
  int nb0 = chunk * (NCHUNK / 16);
  int ko = (l >> 5) * 8;
  for (int st = 0; st < NCHUNK / 16; ++st) {
    size_t aoff = (((size_t)dg * (NS / 16) + nb0 + st) * 64 + l) * 8;
    bf16x8 th = *(const bf16x8*)&XBH[aoff];
    bf16x8 tl = *(const bf16x8*)&XBL[aoff];
    float4 w0 = *(const float4*)&wp[16 * st + ko];
    float4 w1 = *(const float4*)&wp[16 * st + ko + 4];
    float wj[8] = {w0.x, w0.y, w0.z, w0.w, w1.x, w1.y, w1.z, w1.w};
    bf16x8 ah, al;
    #pragma unroll
    for (int j = 0; j < 8; ++j) {
      float xf = bf2f((ushort)th[j]) + bf2f((ushort)tl[j]);
      float zf = wj[j] * xf;
      union { float f; unsigned u; } cz; cz.f = zf;
      ah[j] = (short)(ushort)(cz.u >> 16);
      union { unsigned u; float f; } ch; ch.u = cz.u & 0xffff0000u;
      al[j] = (short)f2bf_rne(zf - ch.f);
    }
    #pragma unroll
    for (int eg = 0; eg < 4; ++eg) {
      size_t boff = (((size_t)eg * (NS / 16) + nb0 + st) * 64 + l) * 8;
      bf16x8 bh = *(const bf16x8*)&XBH[boff];
      bf16x8 bl = *(const bf16x8*)&XBL[boff];
      acc[eg] = __builtin_amdgcn_mfma_f32_32x32x16_bf16(ah, bh, acc[eg], 0, 0, 0);
      acc[eg] = __builtin_amdgcn_mfma_f32_32x32x16_bf16(ah, bl, acc[eg], 0, 0, 0);
      acc[eg] = __builtin_amdgcn_mfma_f32_32x32x16_bf16(al, bh, acc[eg], 0, 0, 0);
    }
  }
  float* __restrict__ S = ws + OFF_CS + (size_t)k * DD * DD;
  int h = l >> 5;
  #pragma unroll
  for (int eg = 0; eg < 4; ++eg) {
    int e = 32 * eg + (l & 31);
    #pragma unroll
    for (int r = 0; r < 16; ++r) {
      int drow = 32 * dg + (r & 3) + 8 * (r >> 2) + 4 * h;
      atomicAdd(&S[drow * DD + e], acc[eg][r]);
    }
  }
}

// new_m = num/sw; new_C = (S - m num^T - num m^T + sw m m^T)/sw + jitter*I.
// Fused convergence flag via last-block counter.
__global__ __launch_bounds__(128) void k_update(float* __restrict__ ws, float* __restrict__ dout,
                                                int guarded, int write_out, int accum_diff) {
  if (guarded && ((const int*)ws)[OFF_DONE]) return;
  __shared__ float red[128];
  int k = blockIdx.x, e = threadIdx.x;
  float sw = ws[OFF_SW + k];
  float inv = 1.f / sw;
  float me = ws[OFF_CUR_M + k * DD + e];
  float ne = ws[OFF_NUM + k * DD + e];
  float* __restrict__ SC = ws + OFF_CS + (size_t)k * DD * DD;
  const float* __restrict__ cm = ws + OFF_CUR_M + k * DD;
  const float* __restrict__ nm = ws + OFF_NUM + k * DD;
  for (int d = 0; d < DD; ++d) {
    float md = cm[d];
    float nd = nm[d];
    float v = (SC[d * DD + e] - md * ne - nd * me + sw * md * me) * inv;
    if (d == e) v += JITTER_;
    SC[d * DD + e] = v;
    if (write_out) dout[1 + KC * DD + k * DD * DD + d * DD + e] = v;
  }
  __syncthreads();
  float newm = ne * inv;
  ws[OFF_CUR_M + k * DD + e] = newm;
  if (write_out) dout[1 + k * DD + e] = newm;
  if (accum_diff) {
    float dm = newm - me;
    red[e] = dm * dm;
    __syncthreads();
    for (int s2 = 64; s2 > 0; s2 >>= 1) {
      if (e < s2) red[e] += red[e + s2];
      __syncthreads();
    }
    if (e == 0) {
      atomicAdd(&ws[OFF_DIFFSQ], red[0]);
      __threadfence();
      int old = atomicAdd((int*)ws + OFF_CTR, 1);
      if (old == KC - 1) {
        float v = atomicAdd(&ws[OFF_DIFFSQ], 0.f);
        if (v <= EPS2_) atomicExch((int*)ws + OFF_DONE, 1);
        atomicExch(&ws[OFF_DIFFSQ], 0.f);
      }
    }
  }
}

__global__ void k_lossfin(const float* __restrict__ weights, const float* __restrict__ ws,
                          float* __restrict__ dout) {
  if (threadIdx.x == 0 && blockIdx.x == 0) {
    float base = 0.f;
    for (int k = 0; k < KC; ++k)
      base += weights[k] * 0.5f * (float)NS * ((float)DD * LOG_2PI_ + ws[OFF_LOGDET + k])
            + ws[OFF_LOSSK + k];
    dout[0] = base;
  }
}

extern "C" void kernel_launch(void* const* d_in, const int* in_sizes, int n_in,
                              void* d_out, int out_size, void* d_ws, size_t ws_size,
                              hipStream_t stream) {
  const float* x       = (const float*)d_in[0];
  const float* means   = (const float*)d_in[1];
  const float* covs    = (const float*)d_in[2];
  const float* weights = (const float*)d_in[3];
  float* out = (float*)d_out;
  float* ws  = (float*)d_ws;

  hipLaunchKernelGGL(k_init_split, dim3(NS / 64), dim3(256), 0, stream, x, means, covs, ws);

  // 8 guarded loop iterations + 1 unguarded final update (u==8)
  for (int u = 0; u < 9; ++u) {
    int guarded = (u < 8) ? 1 : 0;
    hipLaunchKernelGGL(k_chol,    dim3(16),      dim3(256), 0, stream, ws, guarded, 0);
    hipLaunchKernelGGL(k_trinv,   dim3(16),      dim3(256), 0, stream, ws, guarded);
    hipLaunchKernelGGL(k_quad,    dim3(128, 16), dim3(256), 0, stream, ws, weights, guarded, 0);
    hipLaunchKernelGGL(k_scatter, dim3(NS / NCHUNK, 16), dim3(256), 0, stream, ws, guarded);
    hipLaunchKernelGGL(k_update,  dim3(16),      dim3(128), 0, stream, ws, out, guarded,
                       (u == 8) ? 1 : 0, guarded);
  }

  // final log-prob: Cholesky/Linv of c_fin (+logdet), mahalanobis + loss
  hipLaunchKernelGGL(k_chol,    dim3(16),      dim3(256), 0, stream, ws, 0, 1);
  hipLaunchKernelGGL(k_trinv,   dim3(16),      dim3(256), 0, stream, ws, 0);
  hipLaunchKernelGGL(k_quad,    dim3(128, 16), dim3(256), 0, stream, ws, weights, 0, 1);
  hipLaunchKernelGGL(k_lossfin, dim3(1),       dim3(64),  0, stream, weights, ws, out);
}

// Round 9
// 1472.531 us; speedup vs baseline: 1.5777x; 1.0361x over previous
//
#include <hip/hip_runtime.h>
#include <math.h>

// GaussianMixtureLayer: EM loop (<=8 iters, device-side convergence flag) +
// final update + Gaussian log-prob loss. Heavy GEMMs on bf16 MFMA (hi/lo
// 3-term split), operands in FRAGMENT ORDER (wave-contiguous dwordx4 loads).
//   k_quad   : Y = X Linv^T, w = ||y - t||^2 (+ fused num/sw or final loss)
//   k_scatter: S_k = (w.X)^T X   (NCHUNK=1024 to amortize the atomic flush)
//   k_chol   : LDS Cholesky; PANEL=16 wave-synchronous factorization; 512
//              threads (2 waves/SIMD) + q-paired trailing update for latency
//              hiding [256-thread version ran 1 wave/SIMD -> 78us at 1.4%
//              VALUBusy, pure exposed ds_read latency]
//   k_trinv  : TWO-LEVEL blocked Linv: parallel 64x64 diag inverses + two
//              cooperative 64^3 LDS GEMMs.
//   k_update : closed-form mean/cov update + fused convergence flag

#define NS 16384
#define DD 128
#define KC 16
#define JITTER_ 1e-6f
#define EPS2_ 1e-6f            // (1e-3)^2 Frobenius convergence check
#define LOG_2PI_ 1.8378770664093454f
#define NCHUNK 1024            // scatter samples per block

typedef __attribute__((ext_vector_type(8))) short bf16x8;
typedef __attribute__((ext_vector_type(16))) float f32x16;

// workspace float offsets
enum : int {
  OFF_CUR_M  = 0,            // 16*128
  OFF_CS     = 2048,         // 16*128*128 (C, then S accumulator, then new C)
  OFF_LT     = 264192,       // fp32 L^T per k: LT[p][i] = L[i][p]
  OFF_INVD   = 526336,       // 1/L_ii
  OFF_T      = 528384,       // t_k = Linv_k m_k (fp32)
  OFF_LOGDET = 530432,
  OFF_SW     = 530448,
  OFF_NUM    = 530464,       // 16*128
  OFF_W      = 532512,       // w[k][n]
  OFF_LOSSK  = 794656,       // 16 per-k loss partials
  OFF_DIFFSQ = 794672,
  OFF_DONE   = 794673,       // int
  OFF_CTR    = 794674,       // int
  // frag-order bf16 arrays (ushort), 2 floats per 4 ushorts:
  OFF_XAH    = 794676,       // X row-side frags: [ng(512)][ec(4)][ks(2)][l(64)][8]
  OFF_XAL    = 1843252,
  OFF_XBH    = 2891828,      // X^T frags: [eg(4)][nb(1024)][l(64)][8]
  OFF_XBL    = 3940404,
  OFF_LBH    = 4988980,      // Linv frags per k: [k][dg(4)][ec(4)][ks(2)][l(64)][8]
  OFF_LBL    = 5120052,
  WS_FLOATS  = 5251124       // ~21 MB
};

__device__ __forceinline__ float bf2f(ushort u) {
  union { unsigned u; float f; } c; c.u = ((unsigned)u) << 16; return c.f;
}
__device__ __forceinline__ ushort f2bf_rne(float f) {
  union { float f; unsigned u; } c; c.f = f;
  unsigned r = c.u + 0x7fffu + ((c.u >> 16) & 1u);
  return (ushort)(r >> 16);
}
__device__ __forceinline__ ushort f2bf_trunc(float f) {
  union { float f; unsigned u; } c; c.f = f; return (ushort)(c.u >> 16);
}

// XOR-quad swizzle for 128x128 LDS matrix (k_chol).
__device__ __forceinline__ int swz(int r, int c) {
  return (r << 7) + ((((c >> 2) + r) & 31) << 2) + (c & 3);
}

// init state + one-time bf16 hi/lo split of X into frag-order XA (row side)
// and XB (transposed side). Block b handles samples 64b..64b+63.
__global__ __launch_bounds__(256) void k_init_split(const float* __restrict__ x,
                                                    const float* __restrict__ means,
                                                    const float* __restrict__ covs,
                                                    float* __restrict__ ws) {
  __shared__ float xt[64 * 132];
  int b = blockIdx.x, t = threadIdx.x;
  int idx = b * 256 + t;
  for (int i = idx; i < KC * DD * DD; i += 256 * 256) ws[OFF_CS + i] = covs[i];
  if (idx < KC * DD) ws[OFF_CUR_M + idx] = means[idx];
  if (idx == 0) {
    ws[OFF_DIFFSQ] = 0.f;
    ((int*)ws)[OFF_DONE] = 0;
    ((int*)ws)[OFF_CTR]  = 0;
  }
  int n0 = b * 64;
  for (int fi = t; fi < 2048; fi += 256) {
    int n = fi >> 5, q = (fi & 31) * 4;
    *(float4*)&xt[n * 132 + q] = *(const float4*)&x[(size_t)(n0 + n) * DD + q];
  }
  __syncthreads();
  ushort* __restrict__ XAH = (ushort*)(ws + OFF_XAH);
  ushort* __restrict__ XAL = (ushort*)(ws + OFF_XAL);
  ushort* __restrict__ XBH = (ushort*)(ws + OFF_XBH);
  ushort* __restrict__ XBL = (ushort*)(ws + OFF_XBL);
  // XA: n = 32*ng+(l&31), e = 32ec+16ks+8(l>>5)+j
  for (int s = t; s < 1024; s += 256) {
    int l = s & 63, ks = (s >> 6) & 1, ec = (s >> 7) & 3, ngl = (s >> 9) & 1;
    int nl = 32 * ngl + (l & 31);
    int e0 = 32 * ec + 16 * ks + 8 * (l >> 5);
    float vv[8];
    *(float4*)&vv[0] = *(const float4*)&xt[nl * 132 + e0];
    *(float4*)&vv[4] = *(const float4*)&xt[nl * 132 + e0 + 4];
    ushort h[8], lo[8];
    #pragma unroll
    for (int j = 0; j < 8; ++j) {
      h[j]  = f2bf_trunc(vv[j]);
      lo[j] = f2bf_rne(vv[j] - bf2f(h[j]));
    }
    size_t base = ((((size_t)((n0 >> 5) + ngl) * 4 + ec) * 2 + ks) * 64 + l) * 8;
    *(ushort4*)&XAH[base]     = make_ushort4(h[0], h[1], h[2], h[3]);
    *(ushort4*)&XAH[base + 4] = make_ushort4(h[4], h[5], h[6], h[7]);
    *(ushort4*)&XAL[base]     = make_ushort4(lo[0], lo[1], lo[2], lo[3]);
    *(ushort4*)&XAL[base + 4] = make_ushort4(lo[4], lo[5], lo[6], lo[7]);
  }
  // XB: e = 32eg+(l&31), n = 16*nb+8(l>>5)+j
  for (int s = t; s < 1024; s += 256) {
    int l = s & 63, nbl = (s >> 6) & 3, eg = (s >> 8) & 3;
    int e = 32 * eg + (l & 31);
    int nl = 16 * nbl + 8 * (l >> 5);
    ushort h[8], lo[8];
    #pragma unroll
    for (int j = 0; j < 8; ++j) {
      float v = xt[(nl + j) * 132 + e];
      h[j]  = f2bf_trunc(v);
      lo[j] = f2bf_rne(v - bf2f(h[j]));
    }
    size_t base = (((size_t)eg * (NS / 16) + (n0 >> 4) + nbl) * 64 + l) * 8;
    *(ushort4*)&XBH[base]     = make_ushort4(h[0], h[1], h[2], h[3]);
    *(ushort4*)&XBH[base + 4] = make_ushort4(h[4], h[5], h[6], h[7]);
    *(ushort4*)&XBL[base]     = make_ushort4(lo[0], lo[1], lo[2], lo[3]);
    *(ushort4*)&XBL[base + 4] = make_ushort4(lo[4], lo[5], lo[6], lo[7]);
  }
}

// Blocked right-looking Cholesky of C[k] (from OFF_CS) in LDS. PANEL=16:
// wave 0 factorizes the 128x16 panel in registers; all 512 threads apply the
// rank-16 trailing update with q-PAIRING (q and q+32 per thread: row-i panel
// loaded once per pair, two independent FMA chains). Writes fp32 LT + 1/diag
// (+logdet on final), zeroes S/num/sw accumulators.
__global__ __launch_bounds__(512) void k_chol(float* __restrict__ ws, int guarded, int final_pass) {
  if (guarded && ((const int*)ws)[OFF_DONE]) return;
  __shared__ float m[DD * DD];
  int k = blockIdx.x, t = threadIdx.x;
  int l = t & 63, wv = t >> 6;
  float* __restrict__ C = ws + OFF_CS + (size_t)k * DD * DD;
  for (int i = t; i < DD * DD; i += 512) {
    m[swz(i >> 7, i & 127)] = C[i];
    C[i] = 0.f;                      // becomes this iteration's S accumulator
  }
  if (t < DD) ws[OFF_NUM + k * DD + t] = 0.f;
  if (t == 0) {
    ws[OFF_SW + k] = 0.f;
    if (k == 0) ((int*)ws)[OFF_CTR] = 0;
    if (final_pass) ws[OFF_LOSSK + k] = 0.f;
  }
  __syncthreads();

  for (int P = 0; P < DD; P += 16) {
    if (wv == 0) {
      int ra = P + l, rb = P + 64 + l;
      bool va = ra < DD, vb = rb < DD;
      float A[16], B[16];
      if (va) {
        #pragma unroll
        for (int q = 0; q < 4; ++q) {
          float4 v = *(const float4*)&m[swz(ra, P + 4 * q)];
          A[4*q+0] = v.x; A[4*q+1] = v.y; A[4*q+2] = v.z; A[4*q+3] = v.w;
        }
      }
      if (vb) {
        #pragma unroll
        for (int q = 0; q < 4; ++q) {
          float4 v = *(const float4*)&m[swz(rb, P + 4 * q)];
          B[4*q+0] = v.x; B[4*q+1] = v.y; B[4*q+2] = v.z; B[4*q+3] = v.w;
        }
      }
      #pragma unroll
      for (int jj = 0; jj < 16; ++jj) {
        float dj = __shfl(A[jj], jj, 64);
        float sj = sqrtf(dj);
        float inv = 1.f / sj;
        if (va) {
          if (l == jj) A[jj] = sj;
          else if (l > jj) A[jj] *= inv;
        }
        if (vb) B[jj] *= inv;
        #pragma unroll
        for (int jj2 = jj + 1; jj2 < 16; ++jj2) {
          float c = __shfl(A[jj], jj2, 64);
          if (va && l > jj) A[jj2] -= A[jj] * c;
          if (vb) B[jj2] -= B[jj] * c;
        }
      }
      if (va) {
        #pragma unroll
        for (int q = 0; q < 4; ++q)
          *(float4*)&m[swz(ra, P + 4 * q)] = make_float4(A[4*q], A[4*q+1], A[4*q+2], A[4*q+3]);
      }
      if (vb) {
        #pragma unroll
        for (int q = 0; q < 4; ++q)
          *(float4*)&m[swz(rb, P + 4 * q)] = make_float4(B[4*q], B[4*q+1], B[4*q+2], B[4*q+3]);
      }
    }
    __syncthreads();
    // trailing update: m[i][q] -= sum_p L[i][p] L[q][p] for i,q >= R0.
    // q-paired: thread handles q1 = tq+b and q2 = q1+32 together.
    int R0 = P + 16;
    if (R0 < DD) {
      int tq = R0 + (t & 31);
      for (int b = 0; b < 128; b += 64) {
        int q1 = tq + b, q2 = tq + b + 32;
        bool v1 = q1 < DD, v2 = q2 < DD;
        if (v1) {
          float lq1[16], lq2[16];
          #pragma unroll
          for (int p4 = 0; p4 < 4; ++p4) {
            float4 v = *(const float4*)&m[swz(q1, P + 4 * p4)];
            lq1[4*p4+0] = v.x; lq1[4*p4+1] = v.y; lq1[4*p4+2] = v.z; lq1[4*p4+3] = v.w;
          }
          if (v2) {
            #pragma unroll
            for (int p4 = 0; p4 < 4; ++p4) {
              float4 v = *(const float4*)&m[swz(q2, P + 4 * p4)];
              lq2[4*p4+0] = v.x; lq2[4*p4+1] = v.y; lq2[4*p4+2] = v.z; lq2[4*p4+3] = v.w;
            }
          }
          for (int i = R0 + (t >> 5); i < DD; i += 16) {
            float ri[16];
            #pragma unroll
            for (int p4 = 0; p4 < 4; ++p4) {
              float4 v = *(const float4*)&m[swz(i, P + 4 * p4)];
              ri[4*p4+0] = v.x; ri[4*p4+1] = v.y; ri[4*p4+2] = v.z; ri[4*p4+3] = v.w;
            }
            float a1 = m[swz(i, q1)];
            float a2 = v2 ? m[swz(i, q2)] : 0.f;
            #pragma unroll
            for (int p = 0; p < 16; ++p) {
              a1 -= ri[p] * lq1[p];
              if (v2) a2 -= ri[p] * lq2[p];
            }
            m[swz(i, q1)] = a1;
            if (v2) m[swz(i, q2)] = a2;
          }
        }
      }
    }
    __syncthreads();
  }

  float* __restrict__ LT = ws + OFF_LT + (size_t)k * DD * DD;
  for (int idx = t; idx < DD * DD; idx += 512) {
    int p = idx >> 7, i = idx & 127;
    LT[idx] = (i >= p) ? m[swz(i, p)] : 0.f;
  }
  if (t < DD) ws[OFF_INVD + k * DD + t] = 1.f / m[swz(t, t)];
  if (final_pass && t == 0) {
    float ld = 0.f;
    for (int i = 0; i < DD; ++i) ld += logf(m[swz(i, i)]);
    ws[OFF_LOGDET + k] = 2.f * ld;
  }
}

// Two-level blocked triangular inverse. L = [[A,0],[C,B]] (64x64 blocks):
//   Linv = [[Ainv, 0], [-Binv C Ainv, Binv]].
__global__ __launch_bounds__(256) void k_trinv(float* __restrict__ ws, int guarded) {
  if (guarded && ((const int*)ws)[OFF_DONE]) return;
  __shared__ float Zs[DD * 132];   // Linv row-major: Zs[d*132+e] = Linv[d][e]
  __shared__ float Cs[64 * 68];    // Cs[q*68+i] = C[i][q] = L[64+i][q]
  __shared__ float Ws[64 * 68];    // Ws[i*68+j] = W[i][j]
  int k = blockIdx.x, t = threadIdx.x;
  const float* __restrict__ LT   = ws + OFF_LT + (size_t)k * DD * DD;
  const float* __restrict__ invd = ws + OFF_INVD + k * DD;
  if (t < 128) {
    int h = t >> 6, j = t & 63;                    // h uniform per wave
    const float* __restrict__ Lh = LT + (h * 64) * DD + h * 64;
    const float* __restrict__ dv = invd + h * 64;
    float* __restrict__ Zh = Zs + (h * 64) * 132 + h * 64;
    float acc[64];
    #pragma unroll
    for (int i = 0; i < 64; ++i) acc[i] = 0.f;
    #pragma unroll
    for (int p = 0; p < 64; ++p) {
      float zp = (((p == j) ? 1.f : 0.f) - acc[p]) * dv[p];
      Zh[p * 132 + j] = zp;
      #pragma unroll
      for (int i = p + 1; i < 64; ++i) acc[i] += Lh[p * DD + i] * zp;
    }
  } else {
    int u = t - 128;
    for (int s = u; s < 4096; s += 128) {
      int q = s >> 6, i = s & 63;
      Cs[q * 68 + i] = LT[q * DD + 64 + i];
      Zs[(s >> 6) * 132 + 64 + (s & 63)] = 0.f;
    }
  }
  __syncthreads();
  int i0 = (t & 15) * 4, j0 = (t >> 4) * 4;
  {  // GEMM1: W = C * Ainv
    float acc[4][4] = {};
    for (int q = 0; q < 64; ++q) {
      float4 a = *(const float4*)&Cs[q * 68 + i0];
      float4 b = *(const float4*)&Zs[q * 132 + j0];
      float av[4] = {a.x, a.y, a.z, a.w}, bv[4] = {b.x, b.y, b.z, b.w};
      #pragma unroll
      for (int r = 0; r < 4; ++r)
        #pragma unroll
        for (int c = 0; c < 4; ++c) acc[r][c] += av[r] * bv[c];
    }
    #pragma unroll
    for (int r = 0; r < 4; ++r)
      #pragma unroll
      for (int c = 0; c < 4; ++c) Ws[(i0 + r) * 68 + j0 + c] = acc[r][c];
  }
  __syncthreads();
  {  // GEMM2: Linv21 = -Binv * W
    float acc[4][4] = {};
    for (int q0 = 0; q0 < 64; q0 += 4) {
      float4 bi[4], wq[4];
      #pragma unroll
      for (int r = 0; r < 4; ++r)
        bi[r] = *(const float4*)&Zs[(64 + i0 + r) * 132 + 64 + q0];
      #pragma unroll
      for (int s = 0; s < 4; ++s)
        wq[s] = *(const float4*)&Ws[(q0 + s) * 68 + j0];
      #pragma unroll
      for (int r = 0; r < 4; ++r) {
        float br[4] = {bi[r].x, bi[r].y, bi[r].z, bi[r].w};
        #pragma unroll
        for (int s = 0; s < 4; ++s) {
          float wv2[4] = {wq[s].x, wq[s].y, wq[s].z, wq[s].w};
          #pragma unroll
          for (int c = 0; c < 4; ++c) acc[r][c] += br[s] * wv2[c];
        }
      }
    }
    #pragma unroll
    for (int r = 0; r < 4; ++r)
      #pragma unroll
      for (int c = 0; c < 4; ++c) Zs[(64 + i0 + r) * 132 + j0 + c] = -acc[r][c];
  }
  __syncthreads();
  if (t < 128) {   // t = Linv * m
    const float* __restrict__ mk = ws + OFF_CUR_M + k * DD;
    float s0 = 0.f;
    for (int e = 0; e < DD; e += 4) {
      float4 z = *(const float4*)&Zs[t * 132 + e];
      s0 += z.x * mk[e] + z.y * mk[e + 1] + z.z * mk[e + 2] + z.w * mk[e + 3];
    }
    ws[OFF_T + k * DD + t] = s0;
  }
  // frag-order bf16 writes: d=32dg+(l&31), e=32ec+16ks+8(l>>5)+j2
  ushort* __restrict__ LBH = (ushort*)(ws + OFF_LBH) + (size_t)k * 16384;
  ushort* __restrict__ LBL = (ushort*)(ws + OFF_LBL) + (size_t)k * 16384;
  for (int s = t; s < 16384; s += 256) {
    int j2 = s & 7, l = (s >> 3) & 63, ks2 = (s >> 9) & 1, ec = (s >> 10) & 3, dg = (s >> 12) & 3;
    int d = 32 * dg + (l & 31);
    int e = 32 * ec + 16 * ks2 + 8 * (l >> 5) + j2;
    float v = Zs[d * 132 + e];
    ushort hh = f2bf_trunc(v);
    LBH[s] = hh;
    LBL[s] = f2bf_rne(v - bf2f(hh));
  }
}

// w[n,k] = ||X Linv^T - t||^2. Block: 128 samples x full 128 d, 4 waves.
// All operand loads are wave-contiguous 1 KB dwordx4 from frag-order arrays.
__global__ __launch_bounds__(256) void k_quad(float* __restrict__ ws,
                                              const float* __restrict__ wts,
                                              int guarded, int final_pass) {
  if (guarded && ((const int*)ws)[OFF_DONE]) return;
  __shared__ float warr[128];
  int k = blockIdx.y, bx = blockIdx.x, t = threadIdx.x;
  int l = t & 63, wv = t >> 6;
  int n0 = bx * 128;
  const ushort* __restrict__ XAH = (const ushort*)(ws + OFF_XAH);
  const ushort* __restrict__ XAL = (const ushort*)(ws + OFF_XAL);
  const ushort* __restrict__ LBH = (const ushort*)(ws + OFF_LBH) + (size_t)k * 16384;
  const ushort* __restrict__ LBL = (const ushort*)(ws + OFF_LBL) + (size_t)k * 16384;
  f32x16 acc[4] = {};
  size_t ng4 = (size_t)(4 * bx + wv) * 4;
  #pragma unroll
  for (int ec = 0; ec < 4; ++ec) {
    #pragma unroll
    for (int ks = 0; ks < 2; ++ks) {
      size_t aoff = (((ng4 + ec) * 2 + ks) * 64 + l) * 8;
      bf16x8 ah = *(const bf16x8*)&XAH[aoff];
      bf16x8 al = *(const bf16x8*)&XAL[aoff];
      #pragma unroll
      for (int dg = 0; dg < 4; ++dg) {
        size_t boff = ((((size_t)dg * 4 + ec) * 2 + ks) * 64 + l) * 8;
        bf16x8 bh = *(const bf16x8*)&LBH[boff];
        bf16x8 bl = *(const bf16x8*)&LBL[boff];
        acc[dg] = __builtin_amdgcn_mfma_f32_32x32x16_bf16(ah, bh, acc[dg], 0, 0, 0);
        acc[dg] = __builtin_amdgcn_mfma_f32_32x32x16_bf16(ah, bl, acc[dg], 0, 0, 0);
        acc[dg] = __builtin_amdgcn_mfma_f32_32x32x16_bf16(al, bh, acc[dg], 0, 0, 0);
      }
    }
  }
  float tv[4];
  #pragma unroll
  for (int c = 0; c < 4; ++c) tv[c] = ws[OFF_T + k * DD + 32 * c + (l & 31)];
  float part[16];
  #pragma unroll
  for (int r = 0; r < 16; ++r) {
    float s = 0.f;
    #pragma unroll
    for (int c = 0; c < 4; ++c) { float d = acc[c][r] - tv[c]; s += d * d; }
    part[r] = s;
  }
  #pragma unroll
  for (int mk2 = 1; mk2 < 32; mk2 <<= 1)
    #pragma unroll
    for (int r = 0; r < 16; ++r) part[r] += __shfl_xor(part[r], mk2, 64);
  int h = l >> 5;
  if ((l & 31) < 16) {
    int r = l & 31;
    int row = (r & 3) + 8 * (r >> 2) + 4 * h + 32 * wv;   // verified C/D layout
    warr[row] = part[r];
    ws[OFF_W + k * NS + n0 + row] = part[r];
  }
  __syncthreads();
  if (!final_pass) {
    if (t < 128) {
      int d = t;
      int e_ec = d >> 5, e_ks = (d >> 4) & 1, e_h = (d >> 3) & 1, e_j = d & 7;
      float s = 0.f;
      for (int n = 0; n < 128; ++n) {
        size_t a = ((((size_t)(4 * bx + (n >> 5)) * 4 + e_ec) * 2 + e_ks) * 64 +
                    ((e_h << 5) | (n & 31))) * 8 + e_j;
        s += warr[n] * (bf2f(XAH[a]) + bf2f(XAL[a]));
      }
      atomicAdd(&ws[OFF_NUM + k * DD + d], s);
    } else if (t == 128) {
      float s = 0.f;
      for (int n = 0; n < 128; ++n) s += warr[n];
      atomicAdd(&ws[OFF_SW + k], s);
    }
  } else {
    if (t < 64) {
      float s = warr[t] + warr[t + 64];
      #pragma unroll
      for (int mk2 = 1; mk2 < 64; mk2 <<= 1) s += __shfl_xor(s, mk2, 64);
      if (t == 0) atomicAdd(&ws[OFF_LOSSK + k], 0.5f * wts[k] * s);
    }
  }
}

// S_k += (w.X)^T X over NCHUNK samples; operands from frag-order XB arrays
// (wave-contiguous loads); A re-split with w on the fly in registers.
__global__ __launch_bounds__(256) void k_scatter(float* __restrict__ ws, int guarded) {
  if (guarded && ((const int*)ws)[OFF_DONE]) return;
  int k = blockIdx.y, chunk = blockIdx.x, t = threadIdx.x;
  int l = t & 63, dg = t >> 6;
  const ushort* __restrict__ XBH = (const ushort*)(ws + OFF_XBH);
  const ushort* __restrict__ XBL = (const ushort*)(ws + OFF_XBL);
  const float* __restrict__ wp = ws + OFF_W + k * NS + chunk * NCHUNK;
  f32x16 acc[4] = {};
  int nb0 = chunk * (NCHUNK / 16);
  int ko = (l >> 5) * 8;
  for (int st = 0; st < NCHUNK / 16; ++st) {
    size_t aoff = (((size_t)dg * (NS / 16) + nb0 + st) * 64 + l) * 8;
    bf16x8 th = *(const bf16x8*)&XBH[aoff];
    bf16x8 tl = *(const bf16x8*)&XBL[aoff];
    float4 w0 = *(const float4*)&wp[16 * st + ko];
    float4 w1 = *(const float4*)&wp[16 * st + ko + 4];
    float wj[8] = {w0.x, w0.y, w0.z, w0.w, w1.x, w1.y, w1.z, w1.w};
    bf16x8 ah, al;
    #pragma unroll
    for (int j = 0; j < 8; ++j) {
      float xf = bf2f((ushort)th[j]) + bf2f((ushort)tl[j]);
      float zf = wj[j] * xf;
      union { float f; unsigned u; } cz; cz.f = zf;
      ah[j] = (short)(ushort)(cz.u >> 16);
      union { unsigned u; float f; } ch; ch.u = cz.u & 0xffff0000u;
      al[j] = (short)f2bf_rne(zf - ch.f);
    }
    #pragma unroll
    for (int eg = 0; eg < 4; ++eg) {
      size_t boff = (((size_t)eg * (NS / 16) + nb0 + st) * 64 + l) * 8;
      bf16x8 bh = *(const bf16x8*)&XBH[boff];
      bf16x8 bl = *(const bf16x8*)&XBL[boff];
      acc[eg] = __builtin_amdgcn_mfma_f32_32x32x16_bf16(ah, bh, acc[eg], 0, 0, 0);
      acc[eg] = __builtin_amdgcn_mfma_f32_32x32x16_bf16(ah, bl, acc[eg], 0, 0, 0);
      acc[eg] = __builtin_amdgcn_mfma_f32_32x32x16_bf16(al, bh, acc[eg], 0, 0, 0);
    }
  }
  float* __restrict__ S = ws + OFF_CS + (size_t)k * DD * DD;
  int h = l >> 5;
  #pragma unroll
  for (int eg = 0; eg < 4; ++eg) {
    int e = 32 * eg + (l & 31);
    #pragma unroll
    for (int r = 0; r < 16; ++r) {
      int drow = 32 * dg + (r & 3) + 8 * (r >> 2) + 4 * h;
      atomicAdd(&S[drow * DD + e], acc[eg][r]);
    }
  }
}

// new_m = num/sw; new_C = (S - m num^T - num m^T + sw m m^T)/sw + jitter*I.
// Fused convergence flag via last-block counter.
__global__ __launch_bounds__(128) void k_update(float* __restrict__ ws, float* __restrict__ dout,
                                                int guarded, int write_out, int accum_diff) {
  if (guarded && ((const int*)ws)[OFF_DONE]) return;
  __shared__ float red[128];
  int k = blockIdx.x, e = threadIdx.x;
  float sw = ws[OFF_SW + k];
  float inv = 1.f / sw;
  float me = ws[OFF_CUR_M + k * DD + e];
  float ne = ws[OFF_NUM + k * DD + e];
  float* __restrict__ SC = ws + OFF_CS + (size_t)k * DD * DD;
  const float* __restrict__ cm = ws + OFF_CUR_M + k * DD;
  const float* __restrict__ nm = ws + OFF_NUM + k * DD;
  for (int d = 0; d < DD; ++d) {
    float md = cm[d];
    float nd = nm[d];
    float v = (SC[d * DD + e] - md * ne - nd * me + sw * md * me) * inv;
    if (d == e) v += JITTER_;
    SC[d * DD + e] = v;
    if (write_out) dout[1 + KC * DD + k * DD * DD + d * DD + e] = v;
  }
  __syncthreads();
  float newm = ne * inv;
  ws[OFF_CUR_M + k * DD + e] = newm;
  if (write_out) dout[1 + k * DD + e] = newm;
  if (accum_diff) {
    float dm = newm - me;
    red[e] = dm * dm;
    __syncthreads();
    for (int s2 = 64; s2 > 0; s2 >>= 1) {
      if (e < s2) red[e] += red[e + s2];
      __syncthreads();
    }
    if (e == 0) {
      atomicAdd(&ws[OFF_DIFFSQ], red[0]);
      __threadfence();
      int old = atomicAdd((int*)ws + OFF_CTR, 1);
      if (old == KC - 1) {
        float v = atomicAdd(&ws[OFF_DIFFSQ], 0.f);
        if (v <= EPS2_) atomicExch((int*)ws + OFF_DONE, 1);
        atomicExch(&ws[OFF_DIFFSQ], 0.f);
      }
    }
  }
}

__global__ void k_lossfin(const float* __restrict__ weights, const float* __restrict__ ws,
                          float* __restrict__ dout) {
  if (threadIdx.x == 0 && blockIdx.x == 0) {
    float base = 0.f;
    for (int k = 0; k < KC; ++k)
      base += weights[k] * 0.5f * (float)NS * ((float)DD * LOG_2PI_ + ws[OFF_LOGDET + k])
            + ws[OFF_LOSSK + k];
    dout[0] = base;
  }
}

extern "C" void kernel_launch(void* const* d_in, const int* in_sizes, int n_in,
                              void* d_out, int out_size, void* d_ws, size_t ws_size,
                              hipStream_t stream) {
  const float* x       = (const float*)d_in[0];
  const float* means   = (const float*)d_in[1];
  const float* covs    = (const float*)d_in[2];
  const float* weights = (const float*)d_in[3];
  float* out = (float*)d_out;
  float* ws  = (float*)d_ws;

  hipLaunchKernelGGL(k_init_split, dim3(NS / 64), dim3(256), 0, stream, x, means, covs, ws);

  // 8 guarded loop iterations + 1 unguarded final update (u==8)
  for (int u = 0; u < 9; ++u) {
    int guarded = (u < 8) ? 1 : 0;
    hipLaunchKernelGGL(k_chol,    dim3(16),      dim3(512), 0, stream, ws, guarded, 0);
    hipLaunchKernelGGL(k_trinv,   dim3(16),      dim3(256), 0, stream, ws, guarded);
    hipLaunchKernelGGL(k_quad,    dim3(128, 16), dim3(256), 0, stream, ws, weights, guarded, 0);
    hipLaunchKernelGGL(k_scatter, dim3(NS / NCHUNK, 16), dim3(256), 0, stream, ws, guarded);
    hipLaunchKernelGGL(k_update,  dim3(16),      dim3(128), 0, stream, ws, out, guarded,
                       (u == 8) ? 1 : 0, guarded);
  }

  // final log-prob: Cholesky/Linv of c_fin (+logdet), mahalanobis + loss
  hipLaunchKernelGGL(k_chol,    dim3(16),      dim3(512), 0, stream, ws, 0, 1);
  hipLaunchKernelGGL(k_trinv,   dim3(16),      dim3(256), 0, stream, ws, 0);
  hipLaunchKernelGGL(k_quad,    dim3(128, 16), dim3(256), 0, stream, ws, weights, 0, 1);
  hipLaunchKernelGGL(k_lossfin, dim3(1),       dim3(64),  0, stream, weights, ws, out);
}